// Round 6
// baseline (444.182 us; speedup 1.0000x reference)
//
#include <hip/hip_runtime.h>
#include <cstdint>

#define TEMP_C 20.0f

typedef float f32x4 __attribute__((ext_vector_type(4)));
typedef __bf16 bf16x8 __attribute__((ext_vector_type(8)));

// fp32 -> bf16 round-to-nearest-even
__device__ __forceinline__ unsigned short f2bf(float f) {
  union { float f; unsigned int u; } v; v.f = f;
  unsigned int r = v.u + 0x7FFFu + ((v.u >> 16) & 1u);
  return (unsigned short)(r >> 16);
}
__device__ __forceinline__ float bf2f(unsigned short b) {
  union { unsigned int u; float f; } v; v.u = ((unsigned int)b) << 16;
  return v.f;
}

// async global->LDS, 16B per lane (dest = wave-uniform base + lane*16)
__device__ __forceinline__ void gload_lds16(const void* g, void* l) {
  __builtin_amdgcn_global_load_lds(
      (__attribute__((address_space(1))) void*)(g),
      (__attribute__((address_space(3))) void*)(l), 16, 0, 0);
}

// ---------------------------------------------------------------------------
// 1a) partial sum-of-squares, all 6 feature slices in one launch.
struct Src6 { const float* p[6]; };

__global__ __launch_bounds__(256) void colnorm_part6_k(
    Src6 S, float* __restrict__ part)
{
  const int sl = blockIdx.z;
  const float* __restrict__ X = S.p[sl];
  const int C = (sl < 3) ? 2048 : 1024;
  const int cpc = C >> 4;                 // 16 chunks
  __shared__ float red[4][64];
  const int pix = threadIdx.x & 63;
  const int sub = threadIdx.x >> 6;
  const int p = blockIdx.x * 64 + pix;
  const int c0 = blockIdx.y * cpc;
  float s = 0.f;
  if (p < 3600) {
    for (int c = c0 + sub; c < c0 + cpc; c += 4) {
      float v = X[(size_t)c * 3600 + p];
      s += v * v;
    }
  }
  red[sub][pix] = s;
  __syncthreads();
  if (sub == 0 && p < 3600) {
    part[(size_t)(sl * 16 + blockIdx.y) * 3600 + p] =
        red[0][pix] + red[1][pix] + red[2][pix] + red[3][pix];
  }
}

// 1b) finish all 6 slices
__global__ __launch_bounds__(256) void colnorm_fin6_k(
    const float* __restrict__ part, float* __restrict__ invn)
{
  const int z = blockIdx.y;
  const int p = blockIdx.x * 256 + threadIdx.x;
  if (p >= 3600) return;
  float s = 0.f;
  #pragma unroll
  for (int j = 0; j < 16; ++j) s += part[(size_t)(z * 16 + j) * 3600 + p];
  invn[(size_t)z * 3600 + p] = 1.0f / fmaxf(sqrtf(s), 1e-12f);
}

// ---------------------------------------------------------------------------
// 2) fused transpose+scale+bf16 for BOTH pyramid levels of one feature set
__global__ __launch_bounds__(256) void tpose2_k(
    const float* __restrict__ X4, const float* __restrict__ X3,
    const float* __restrict__ i4, const float* __restrict__ i3,
    const float* __restrict__ wch, int usew, unsigned short* __restrict__ T)
{
  __shared__ float tile[32][33];
  const int tx = threadIdx.x, ty = threadIdx.y;
  const int y = blockIdx.y;
  const float* X; const float* inv; int c0, cdst; float mult;
  if (y < 64) { X = X4; inv = i4; c0 = y * 32;        cdst = c0;        mult = usew ? TEMP_C * wch[0] : 1.0f; }
  else        { X = X3; inv = i3; c0 = (y - 64) * 32; cdst = 2048 + c0; mult = usew ? TEMP_C * wch[1] : 1.0f; }
  const int p0 = blockIdx.x * 32;
  #pragma unroll
  for (int i = 0; i < 4; ++i) {
    int c = c0 + ty + i * 8, p = p0 + tx;
    tile[ty + i * 8][tx] = (p < 3600) ? X[(size_t)c * 3600 + p] : 0.f;
  }
  __syncthreads();
  #pragma unroll
  for (int i = 0; i < 4; ++i) {
    int p = p0 + ty + i * 8;
    if (p < 3600) {
      float sc = inv[p] * mult;
      T[(size_t)p * 3072 + cdst + tx] = f2bf(tile[tx][ty + i * 8] * sc);
    }
  }
}

// ---------------------------------------------------------------------------
// 3) V cast: f_s slice (512, 3600) fp32 -> V (512, 3840) bf16 (pad pre-zeroed)
__global__ void castv_k(const float* __restrict__ X, unsigned short* __restrict__ V)
{
  int i = blockIdx.x * 256 + threadIdx.x;
  if (i >= 512 * 3600) return;
  int c = i / 3600, s = i - c * 3600;
  V[(size_t)c * 3840 + s] = f2bf(X[i]);
}

// ---------------------------------------------------------------------------
// 4) 256x256 GEMM, 8-phase schedule with COUNTED vmcnt (T3+T4+T5), BK=64,
//    2 LDS slots, XOR-swizzled (zero-conflict, verified round 4).
//    Staging of tile t+1 spread: A halves @ phase 0, B-h0 @ phase 1,
//    B-h1 @ phase 2. ONE counted wait per K-tile at phase 0: after issuing
//    t+1's A stage (4 loads), vmcnt(4) confirms tile t's 8 loads landed
//    while t+1's stay in flight (never drains mid-loop; m218 T4).
//    Slot-reuse safety: phase 3's end barrier follows lgkmcnt(0) (reads
//    retired) before any t+2 staging into the same slot at t+1 phase 0.
__global__ __launch_bounds__(512, 2) void gemm256_k(
    const unsigned short* __restrict__ A, const unsigned short* __restrict__ B,
    float* __restrict__ C, int K, int lda, int ldb, int ldc, int nbn)
{
  __shared__ __align__(16) unsigned short As[2][256 * 64];
  __shared__ __align__(16) unsigned short Bs[2][256 * 64];

  const int tid  = threadIdx.x;
  const int lane = tid & 63;
  const int wave = tid >> 6;
  const int wrow = wave >> 2;   // 0..1
  const int wcol = wave & 3;    // 0..3

  // XCD-aware bijective block remap (m204)
  const int nwg = gridDim.x;
  const int q8 = nwg >> 3, r8 = nwg & 7;
  const int xcd = blockIdx.x & 7, bidx = blockIdx.x >> 3;
  const int wg = (xcd < r8 ? xcd * (q8 + 1) : r8 * (q8 + 1) + (xcd - r8) * q8) + bidx;
  const long Arow0 = (long)(wg / nbn) * 256;
  const long Brow0 = (long)(wg % nbn) * 256;

  // staging sources: thread handles chunks c = q*512+tid (q=0..3) per operand.
  // chunk c holds global (row=c>>3, g=(c&7)^(row&7)); LDS dest = c*16B (linear).
  const unsigned short* sA[4];
  const unsigned short* sB[4];
  #pragma unroll
  for (int q = 0; q < 4; ++q) {
    const int c = q * 512 + tid;
    const int row = c >> 3;
    const int g = (c & 7) ^ (row & 7);
    sA[q] = A + (Arow0 + row) * (long)lda + g * 8;
    sB[q] = B + (Brow0 + row) * (long)ldb + g * 8;
  }

  // half-tile stages: half H of tile tt (q = 2H, 2H+1), slot = tt&1
  #define STAGE_A(tt, H) do {                                              \
    const long _ko = (long)(tt) * 64;                                      \
    gload_lds16(sA[2*(H)]   + _ko, &As[(tt)&1][((2*(H))*512   + tid)*8]);  \
    gload_lds16(sA[2*(H)+1] + _ko, &As[(tt)&1][((2*(H)+1)*512 + tid)*8]);  \
  } while (0)
  #define STAGE_B(tt, H) do {                                              \
    const long _ko = (long)(tt) * 64;                                      \
    gload_lds16(sB[2*(H)]   + _ko, &Bs[(tt)&1][((2*(H))*512   + tid)*8]);  \
    gload_lds16(sB[2*(H)+1] + _ko, &Bs[(tt)&1][((2*(H)+1)*512 + tid)*8]);  \
  } while (0)

  #define BAR   asm volatile("s_barrier" ::: "memory")
  #define LGKM0 do { asm volatile("s_waitcnt lgkmcnt(0)" ::: "memory");    \
                     __builtin_amdgcn_sched_barrier(0); } while (0)

  // read offsets (ushort idx): frag(R, g) at R*64 + (g ^ (R&7))*8
  const int ln15 = lane & 15, lnk = lane >> 4, rx = ln15 & 7;
  const int aR = wrow * 128 + ln15;
  const int bR = wcol * 64 + ln15;
  const int aoff0 = aR * 64 + ((lnk)     ^ rx) * 8;
  const int aoff1 = aR * 64 + ((lnk + 4) ^ rx) * 8;
  const int boff0 = bR * 64 + ((lnk)     ^ rx) * 8;
  const int boff1 = bR * 64 + ((lnk + 4) ^ rx) * 8;

  f32x4 acc[8][4] = {};
  const int NT = K >> 6;   // 64-wide K-tiles

  // prologue: stage tile 0 fully (no wait; t=0 phase 0's vmcnt(4) covers it)
  STAGE_A(0, 0); STAGE_A(0, 1); STAGE_B(0, 0); STAGE_B(0, 1);

  for (int t = 0; t < NT; ++t) {
    const int s = t & 1;
    const bool pf = (t + 1 < NT);
    bf16x8 a[4], b[4];

    // ---- phase 0: stage A(t+1); counted wait; MFMA rows 0-3, k-half 0
    if (pf) {
      STAGE_A(t + 1, 0); STAGE_A(t + 1, 1);
      asm volatile("s_waitcnt vmcnt(4)" ::: "memory");  // tile t landed; t+1 A in flight
    } else {
      asm volatile("s_waitcnt vmcnt(0)" ::: "memory");
    }
    BAR;                                                // slot s visible to all waves
    #pragma unroll
    for (int i = 0; i < 4; ++i) a[i] = *(const bf16x8*)&As[s][aoff0 + i * 1024];
    #pragma unroll
    for (int j = 0; j < 4; ++j) b[j] = *(const bf16x8*)&Bs[s][boff0 + j * 1024];
    LGKM0;
    __builtin_amdgcn_s_setprio(1);
    #pragma unroll
    for (int i = 0; i < 4; ++i)
      #pragma unroll
      for (int j = 0; j < 4; ++j)
        acc[i][j] = __builtin_amdgcn_mfma_f32_16x16x32_bf16(a[i], b[j], acc[i][j], 0, 0, 0);
    __builtin_amdgcn_s_setprio(0);
    BAR;

    // ---- phase 1: rows 4-7, k-half 0 (reuse b); stage B(t+1) h0
    #pragma unroll
    for (int i = 0; i < 4; ++i) a[i] = *(const bf16x8*)&As[s][aoff0 + (4 + i) * 1024];
    if (pf) STAGE_B(t + 1, 0);
    BAR; LGKM0;
    __builtin_amdgcn_s_setprio(1);
    #pragma unroll
    for (int i = 0; i < 4; ++i)
      #pragma unroll
      for (int j = 0; j < 4; ++j)
        acc[4 + i][j] = __builtin_amdgcn_mfma_f32_16x16x32_bf16(a[i], b[j], acc[4 + i][j], 0, 0, 0);
    __builtin_amdgcn_s_setprio(0);
    BAR;

    // ---- phase 2: rows 0-3, k-half 1; stage B(t+1) h1
    #pragma unroll
    for (int i = 0; i < 4; ++i) a[i] = *(const bf16x8*)&As[s][aoff1 + i * 1024];
    #pragma unroll
    for (int j = 0; j < 4; ++j) b[j] = *(const bf16x8*)&Bs[s][boff1 + j * 1024];
    if (pf) STAGE_B(t + 1, 1);
    BAR; LGKM0;
    __builtin_amdgcn_s_setprio(1);
    #pragma unroll
    for (int i = 0; i < 4; ++i)
      #pragma unroll
      for (int j = 0; j < 4; ++j)
        acc[i][j] = __builtin_amdgcn_mfma_f32_16x16x32_bf16(a[i], b[j], acc[i][j], 0, 0, 0);
    __builtin_amdgcn_s_setprio(0);
    BAR;

    // ---- phase 3: rows 4-7, k-half 1 (reuse b); end barrier fences slot reuse
    #pragma unroll
    for (int i = 0; i < 4; ++i) a[i] = *(const bf16x8*)&As[s][aoff1 + (4 + i) * 1024];
    BAR; LGKM0;
    __builtin_amdgcn_s_setprio(1);
    #pragma unroll
    for (int i = 0; i < 4; ++i)
      #pragma unroll
      for (int j = 0; j < 4; ++j)
        acc[4 + i][j] = __builtin_amdgcn_mfma_f32_16x16x32_bf16(a[i], b[j], acc[4 + i][j], 0, 0, 0);
    __builtin_amdgcn_s_setprio(0);
    BAR;
  }
  #undef STAGE_A
  #undef STAGE_B
  #undef BAR
  #undef LGKM0

  // epilogue: D row = (lane>>4)*4 + reg, col = lane&15
  const int rb = lnk * 4;
  #pragma unroll
  for (int i = 0; i < 8; ++i) {
    #pragma unroll
    for (int ii = 0; ii < 4; ++ii) {
      long m = Arow0 + wrow * 128 + i * 16 + rb + ii;
      float* cp = C + m * (long)ldc + Brow0 + wcol * 64 + ln15;
      #pragma unroll
      for (int j = 0; j < 4; ++j) cp[j * 16] = acc[i][j][ii];
    }
  }
}

// ---------------------------------------------------------------------------
// 5) 128x128 GEMM (m97 structure) for PV; blockIdx.z = split-K chunk.
//    C is bf16 partials: C[m][n] (+)= sum_k A[m][k+z*zk]*B[n][k+z*zk].
__global__ __launch_bounds__(256) void gemm_pv_k(
    const unsigned short* __restrict__ A, const unsigned short* __restrict__ B,
    unsigned short* __restrict__ C, int K, int lda, int ldb, int ldc,
    long zk, long zc, int accumulate)
{
  A += (long)blockIdx.z * zk;
  B += (long)blockIdx.z * zk;
  C += (long)blockIdx.z * zc;
  __shared__ __align__(16) unsigned short As[128 * 32];
  __shared__ __align__(16) unsigned short Bs[128 * 32];
  const int tid = threadIdx.x;
  const int lane = tid & 63;
  const int wave = tid >> 6;
  const int wm = (wave >> 1) * 64;
  const int wn = (wave & 1) * 64;
  const long Arow0 = (long)blockIdx.x * 128;
  const long Brow0 = (long)blockIdx.y * 128;

  f32x4 acc[4][4] = {};
  const int r  = lane & 15;
  const int kb = (lane >> 4) * 8;

  for (int k0 = 0; k0 < K; k0 += 32) {
    #pragma unroll
    for (int pass = 0; pass < 2; ++pass) {
      const int chunk = pass * 4 + wave;
      const int m  = chunk * 16 + (lane >> 2);
      const int ke = (lane & 3) * 8;
      gload_lds16(A + (Arow0 + m) * (long)lda + k0 + ke, &As[chunk * 512 + lane * 8]);
      gload_lds16(B + (Brow0 + m) * (long)ldb + k0 + ke, &Bs[chunk * 512 + lane * 8]);
    }
    __syncthreads();

    bf16x8 af[4], bfr[4];
    #pragma unroll
    for (int f = 0; f < 4; ++f) {
      af[f]  = *(const bf16x8*)&As[(wm + f * 16 + r) * 32 + kb];
      bfr[f] = *(const bf16x8*)&Bs[(wn + f * 16 + r) * 32 + kb];
    }
    #pragma unroll
    for (int i = 0; i < 4; ++i)
      #pragma unroll
      for (int j = 0; j < 4; ++j)
        acc[i][j] = __builtin_amdgcn_mfma_f32_16x16x32_bf16(af[i], bfr[j], acc[i][j], 0, 0, 0);
    __syncthreads();
  }

  const int rb = (lane >> 4) * 4;
  const int cn = lane & 15;
  #pragma unroll
  for (int i = 0; i < 4; ++i) {
    #pragma unroll
    for (int ii = 0; ii < 4; ++ii) {
      long m = Arow0 + wm + i * 16 + rb + ii;
      unsigned short* cp = C + m * (long)ldc + Brow0 + wn + cn;
      #pragma unroll
      for (int j = 0; j < 4; ++j) {
        float v = acc[i][j][ii];
        if (accumulate) v += bf2f(cp[j * 16]);
        cp[j * 16] = f2bf(v);
      }
    }
  }
}

// ---------------------------------------------------------------------------
// 6) row softmax, in-place fp32 -> bf16 (row = 3840 fp32; PV lda = 7680)
__global__ __launch_bounds__(256) void softmax_rows_k(float* __restrict__ logits)
{
  const int q = blockIdx.x;
  float* row = logits + (size_t)q * 3840;
  unsigned short* orow = (unsigned short*)row;
  const int tid = threadIdx.x;
  float v[15];
  float mx = -1e30f;
  #pragma unroll
  for (int j = 0; j < 15; ++j) {
    int s = tid + j * 256;
    float x = (s < 3600) ? row[s] : -1e30f;
    v[j] = x;
    mx = fmaxf(mx, x);
  }
  #pragma unroll
  for (int o = 32; o > 0; o >>= 1) mx = fmaxf(mx, __shfl_xor(mx, o));
  __shared__ float wmax[4], wsum[4];
  if ((tid & 63) == 0) wmax[tid >> 6] = mx;
  __syncthreads();
  mx = fmaxf(fmaxf(wmax[0], wmax[1]), fmaxf(wmax[2], wmax[3]));
  float sum = 0.f;
  #pragma unroll
  for (int j = 0; j < 15; ++j) {
    int s = tid + j * 256;
    float e = (s < 3600) ? __expf(v[j] - mx) : 0.f;
    v[j] = e;
    sum += e;
  }
  #pragma unroll
  for (int o = 32; o > 0; o >>= 1) sum += __shfl_xor(sum, o);
  if ((tid & 63) == 0) wsum[tid >> 6] = sum;
  __syncthreads();
  sum = wsum[0] + wsum[1] + wsum[2] + wsum[3];
  const float inv = 1.0f / sum;
  #pragma unroll
  for (int j = 0; j < 15; ++j) {
    int s = tid + j * 256;
    orow[s] = (s < 3600) ? f2bf(v[j] * inv) : (unsigned short)0;
  }
}

// ---------------------------------------------------------------------------
// 7) out[c][p] = 0.5*f_q[c][p] + 0.25*sum_z P[z][p][c]   (bf16 partials)
__global__ __launch_bounds__(256) void final_blend_k(
    const unsigned short* __restrict__ P, const float* __restrict__ fq,
    float* __restrict__ out)
{
  __shared__ float t[32][33];
  const int tx = threadIdx.x, ty = threadIdx.y;
  const int p0 = blockIdx.x * 32, c0 = blockIdx.y * 32;
  const long ZC = 3840L * 512;
  #pragma unroll
  for (int i = 0; i < 4; ++i) {
    int p = p0 + ty + i * 8, c = c0 + tx;
    float s = 0.f;
    if (p < 3600) {
      size_t o = (size_t)p * 512 + c;
      #pragma unroll
      for (int z = 0; z < 6; ++z) s += bf2f(P[o + (size_t)z * ZC]);
    }
    t[ty + i * 8][tx] = s;
  }
  __syncthreads();
  #pragma unroll
  for (int i = 0; i < 4; ++i) {
    int c = c0 + ty + i * 8, p = p0 + tx;
    if (p < 3600) {
      size_t o = (size_t)c * 3600 + p;
      out[o] = 0.5f * fq[o] + 0.25f * t[tx][ty + i * 8];
    }
  }
}

// ---------------------------------------------------------------------------
extern "C" void kernel_launch(void* const* d_in, const int* in_sizes, int n_in,
                              void* d_out, int out_size, void* d_ws, size_t ws_size,
                              hipStream_t stream) {
  const float* fq3 = (const float*)d_in[0];
  const float* fq4 = (const float*)d_in[1];
  const float* fs3 = (const float*)d_in[2];
  const float* fs4 = (const float*)d_in[3];
  const float* f_q = (const float*)d_in[4];
  const float* f_s = (const float*)d_in[5];
  const float* wch = (const float*)d_in[6];
  float* out = (float*)d_out;

  const size_t HW = 3600, MP = 3840, KC = 3072, CH = 512;

  // workspace (~134 MB)
  unsigned short* QT = (unsigned short*)d_ws;    // (MP, KC) bf16, query (TEMP*w folded)
  unsigned short* ST = QT + MP * KC;             // (MP, KC) bf16, support (per batch)
  unsigned short* V  = ST + MP * KC;             // (CH, MP) bf16 (per batch)
  float* logits = (float*)(V + CH * MP);         // (MP, MP) fp32; softmax -> bf16 in place
  unsigned short* Pb = (unsigned short*)(logits + MP * MP);  // 6 x (MP, CH) bf16 partials
  float* invn = (float*)(Pb + 6 * MP * CH);      // 6 x 3600
  float* part = logits;                          // norm scratch (consumed pre-GEMM)

  hipMemsetAsync(QT + HW * KC, 0, (MP - HW) * KC * 2, stream);
  hipMemsetAsync(ST + HW * KC, 0, (MP - HW) * KC * 2, stream);
  hipMemsetAsync(V, 0, CH * MP * 2, stream);

  Src6 S;
  S.p[0] = fq4; S.p[1] = fs4; S.p[2] = fs4 + 2048 * HW;
  S.p[3] = fq3; S.p[4] = fs3; S.p[5] = fs3 + 1024 * HW;
  colnorm_part6_k<<<dim3(57, 16, 6), 256, 0, stream>>>(S, part);
  colnorm_fin6_k<<<dim3(15, 6), 256, 0, stream>>>(part, invn);

  dim3 tb(32, 8);
  tpose2_k<<<dim3(113, 96), tb, 0, stream>>>(fq4, fq3, invn + 0 * HW, invn + 3 * HW,
                                             wch, 1, QT);

  for (int b = 0; b < 2; ++b) {
    castv_k<<<7200, 256, 0, stream>>>(f_s + (size_t)b * CH * HW, V);
    tpose2_k<<<dim3(113, 96), tb, 0, stream>>>(
        fs4 + (size_t)b * 2048 * HW, fs3 + (size_t)b * 1024 * HW,
        invn + (1 + b) * HW, invn + (4 + b) * HW, wch, 0, ST);

    gemm256_k<<<225, 512, 0, stream>>>(QT, ST, logits, 3072, 3072, 3072, 3840, 15);

    softmax_rows_k<<<3600, 256, 0, stream>>>(logits);

    // PV split-K=6, bf16 partials: P[z][q][c] (+)= sum_{s in chunk z} attn[q][s]*V[c][s]
    gemm_pv_k<<<dim3(30, 4, 6), 256, 0, stream>>>(
        (const unsigned short*)logits, V, Pb, 640, 7680, 3840, 512,
        640L, 3840L * 512, b);
  }

  final_blend_k<<<dim3(113, 16), tb, 0, stream>>>(Pb, f_q, out);
}

// Round 7
// 431.288 us; speedup vs baseline: 1.0299x; 1.0299x over previous
//
#include <hip/hip_runtime.h>
#include <cstdint>

#define TEMP_C 20.0f

typedef float f32x4 __attribute__((ext_vector_type(4)));
typedef __bf16 bf16x8 __attribute__((ext_vector_type(8)));

// fp32 -> bf16 round-to-nearest-even
__device__ __forceinline__ unsigned short f2bf(float f) {
  union { float f; unsigned int u; } v; v.f = f;
  unsigned int r = v.u + 0x7FFFu + ((v.u >> 16) & 1u);
  return (unsigned short)(r >> 16);
}
__device__ __forceinline__ float bf2f(unsigned short b) {
  union { unsigned int u; float f; } v; v.u = ((unsigned int)b) << 16;
  return v.f;
}

// async global->LDS, 16B per lane (dest = wave-uniform base + lane*16)
__device__ __forceinline__ void gload_lds16(const void* g, void* l) {
  __builtin_amdgcn_global_load_lds(
      (__attribute__((address_space(1))) void*)(g),
      (__attribute__((address_space(3))) void*)(l), 16, 0, 0);
}

// ---------------------------------------------------------------------------
// 1a) partial sum-of-squares, all 6 feature slices in one launch.
struct Src6 { const float* p[6]; };

__global__ __launch_bounds__(256) void colnorm_part6_k(
    Src6 S, float* __restrict__ part)
{
  const int sl = blockIdx.z;
  const float* __restrict__ X = S.p[sl];
  const int C = (sl < 3) ? 2048 : 1024;
  const int cpc = C >> 4;                 // 16 chunks
  __shared__ float red[4][64];
  const int pix = threadIdx.x & 63;
  const int sub = threadIdx.x >> 6;
  const int p = blockIdx.x * 64 + pix;
  const int c0 = blockIdx.y * cpc;
  float s = 0.f;
  if (p < 3600) {
    for (int c = c0 + sub; c < c0 + cpc; c += 4) {
      float v = X[(size_t)c * 3600 + p];
      s += v * v;
    }
  }
  red[sub][pix] = s;
  __syncthreads();
  if (sub == 0 && p < 3600) {
    part[(size_t)(sl * 16 + blockIdx.y) * 3600 + p] =
        red[0][pix] + red[1][pix] + red[2][pix] + red[3][pix];
  }
}

// 1b) finish all 6 slices
__global__ __launch_bounds__(256) void colnorm_fin6_k(
    const float* __restrict__ part, float* __restrict__ invn)
{
  const int z = blockIdx.y;
  const int p = blockIdx.x * 256 + threadIdx.x;
  if (p >= 3600) return;
  float s = 0.f;
  #pragma unroll
  for (int j = 0; j < 16; ++j) s += part[(size_t)(z * 16 + j) * 3600 + p];
  invn[(size_t)z * 3600 + p] = 1.0f / fmaxf(sqrtf(s), 1e-12f);
}

// ---------------------------------------------------------------------------
// 2) fused transpose+scale+bf16 for BOTH pyramid levels of one feature set
__global__ __launch_bounds__(256) void tpose2_k(
    const float* __restrict__ X4, const float* __restrict__ X3,
    const float* __restrict__ i4, const float* __restrict__ i3,
    const float* __restrict__ wch, int usew, unsigned short* __restrict__ T)
{
  __shared__ float tile[32][33];
  const int tx = threadIdx.x, ty = threadIdx.y;
  const int y = blockIdx.y;
  const float* X; const float* inv; int c0, cdst; float mult;
  if (y < 64) { X = X4; inv = i4; c0 = y * 32;        cdst = c0;        mult = usew ? TEMP_C * wch[0] : 1.0f; }
  else        { X = X3; inv = i3; c0 = (y - 64) * 32; cdst = 2048 + c0; mult = usew ? TEMP_C * wch[1] : 1.0f; }
  const int p0 = blockIdx.x * 32;
  #pragma unroll
  for (int i = 0; i < 4; ++i) {
    int c = c0 + ty + i * 8, p = p0 + tx;
    tile[ty + i * 8][tx] = (p < 3600) ? X[(size_t)c * 3600 + p] : 0.f;
  }
  __syncthreads();
  #pragma unroll
  for (int i = 0; i < 4; ++i) {
    int p = p0 + ty + i * 8;
    if (p < 3600) {
      float sc = inv[p] * mult;
      T[(size_t)p * 3072 + cdst + tx] = f2bf(tile[tx][ty + i * 8] * sc);
    }
  }
}

// ---------------------------------------------------------------------------
// 3) V cast: f_s slice (512, 3600) fp32 -> V (512, 3840) bf16 (pad pre-zeroed)
__global__ void castv_k(const float* __restrict__ X, unsigned short* __restrict__ V)
{
  int i = blockIdx.x * 256 + threadIdx.x;
  if (i >= 512 * 3600) return;
  int c = i / 3600, s = i - c * 3600;
  V[(size_t)c * 3840 + s] = f2bf(X[i]);
}

// ---------------------------------------------------------------------------
// 4) 256x256 GEMM, BK=32, 4 LDS slots, depth-3 prefetch, counted vmcnt.
//    2 phases/K-tile, 16 MFMA each; reads issue BEFORE each barrier
//    (in flight during barrier wait — m201 template order).
//    During tile t: phase A stages A-chunks of tile t+3, phase B stages
//    B-chunks. Tile-boundary wait = vmcnt(8): tile t+1 (issued 2 tiles ago)
//    landed; tiles t+2,t+3 (8 loads) stay in flight. Never drains mid-loop.
//    Swizzle (64B rows): chunk(row,g') holds global g = g'^((row>>1)&3);
//    a wave's ds_read_b128 is then a bijective permutation of a contiguous
//    1KB -> provably bank-conflict-free. Linear LDS dest (gload_lds req),
//    inverse-swizzled global src, swizzled read offsets (rule #21).
__global__ __launch_bounds__(512, 2) void gemm256_k(
    const unsigned short* __restrict__ A, const unsigned short* __restrict__ B,
    float* __restrict__ C, int K, int lda, int ldb, int ldc, int nbn)
{
  __shared__ __align__(16) unsigned short As[4][256 * 32];
  __shared__ __align__(16) unsigned short Bs[4][256 * 32];

  const int tid  = threadIdx.x;
  const int lane = tid & 63;
  const int wave = tid >> 6;
  const int wrow = wave >> 2;   // 0..1
  const int wcol = wave & 3;    // 0..3

  // XCD-aware bijective block remap (m204)
  const int nwg = gridDim.x;
  const int q8 = nwg >> 3, r8 = nwg & 7;
  const int xcd = blockIdx.x & 7, bidx = blockIdx.x >> 3;
  const int wg = (xcd < r8 ? xcd * (q8 + 1) : r8 * (q8 + 1) + (xcd - r8) * q8) + bidx;
  const long Arow0 = (long)(wg / nbn) * 256;
  const long Brow0 = (long)(wg % nbn) * 256;

  // staging: 1024 chunks of 16B per operand per slot; thread owns c = tid, 512+tid.
  // LDS dest linear at c*16B; chunk c <-> (row=c>>2, g'=c&3); global g = g'^((row>>1)&3)
  const unsigned short* sA[2];
  const unsigned short* sB[2];
  #pragma unroll
  for (int q = 0; q < 2; ++q) {
    const int c = q * 512 + tid;
    const int row = c >> 2;
    const int g = (c & 3) ^ ((row >> 1) & 3);
    sA[q] = A + (Arow0 + row) * (long)lda + g * 8;
    sB[q] = B + (Brow0 + row) * (long)ldb + g * 8;
  }

  #define STAGE_A2(tt) do { const long _ko = (long)(tt) * 32; const int _sl = (tt) & 3; \
    gload_lds16(sA[0] + _ko, &As[_sl][tid * 8]);                                        \
    gload_lds16(sA[1] + _ko, &As[_sl][(512 + tid) * 8]); } while (0)
  #define STAGE_B2(tt) do { const long _ko = (long)(tt) * 32; const int _sl = (tt) & 3; \
    gload_lds16(sB[0] + _ko, &Bs[_sl][tid * 8]);                                        \
    gload_lds16(sB[1] + _ko, &Bs[_sl][(512 + tid) * 8]); } while (0)

  #define BAR   asm volatile("s_barrier" ::: "memory")
  #define LGKM0 do { asm volatile("s_waitcnt lgkmcnt(0)" ::: "memory");    \
                     __builtin_amdgcn_sched_barrier(0); } while (0)

  // read offsets (ushort): row R, k-group lnk -> R*32 + (lnk^((R>>1)&3))*8;
  // R = 16*base + ln15  =>  (R>>1)&3 = (ln15>>1)&3 (lane-only)
  const int ln15 = lane & 15, lnk = lane >> 4;
  const int swz = (lnk ^ ((ln15 >> 1) & 3)) * 8;
  const int aoff = (wrow * 128 + ln15) * 32 + swz;
  const int boff = (wcol * 64 + ln15) * 32 + swz;

  f32x4 acc[8][4] = {};
  const int NT = K >> 5;   // 32-wide K-tiles (96)

  // prologue: stage tiles 0,1,2 (12 loads); wait tile 0 (8 = tiles 1,2 in flight)
  STAGE_A2(0); STAGE_B2(0);
  STAGE_A2(1); STAGE_B2(1);
  STAGE_A2(2); STAGE_B2(2);
  asm volatile("s_waitcnt vmcnt(8)" ::: "memory");
  BAR;

  for (int t = 0; t < NT; ++t) {
    const int sl = t & 3;
    bf16x8 a[4], b[4];

    // ---- phase A: rows 0-3 (reads in flight across the barrier)
    #pragma unroll
    for (int i = 0; i < 4; ++i) a[i] = *(const bf16x8*)&As[sl][aoff + i * 512];
    #pragma unroll
    for (int j = 0; j < 4; ++j) b[j] = *(const bf16x8*)&Bs[sl][boff + j * 512];
    if (t + 3 < NT) STAGE_A2(t + 3);
    BAR; LGKM0;
    __builtin_amdgcn_s_setprio(1);
    #pragma unroll
    for (int i = 0; i < 4; ++i)
      #pragma unroll
      for (int j = 0; j < 4; ++j)
        acc[i][j] = __builtin_amdgcn_mfma_f32_16x16x32_bf16(a[i], b[j], acc[i][j], 0, 0, 0);
    __builtin_amdgcn_s_setprio(0);
    BAR;

    // ---- phase B: rows 4-7 (reuse b)
    #pragma unroll
    for (int i = 0; i < 4; ++i) a[i] = *(const bf16x8*)&As[sl][aoff + (4 + i) * 512];
    if (t + 3 < NT) STAGE_B2(t + 3);
    BAR; LGKM0;
    __builtin_amdgcn_s_setprio(1);
    #pragma unroll
    for (int i = 0; i < 4; ++i)
      #pragma unroll
      for (int j = 0; j < 4; ++j)
        acc[4 + i][j] = __builtin_amdgcn_mfma_f32_16x16x32_bf16(a[i], b[j], acc[4 + i][j], 0, 0, 0);
    __builtin_amdgcn_s_setprio(0);

    // tile boundary: ensure tile t+1 landed; keep t+2/t+3 in flight
    if (t + 1 < NT) {
      if (t + 3 < NT)      asm volatile("s_waitcnt vmcnt(8)" ::: "memory");
      else if (t + 2 < NT) asm volatile("s_waitcnt vmcnt(4)" ::: "memory");
      else                 asm volatile("s_waitcnt vmcnt(0)" ::: "memory");
      BAR;
    }
  }
  #undef STAGE_A2
  #undef STAGE_B2
  #undef BAR
  #undef LGKM0

  // epilogue: D row = (lane>>4)*4 + reg, col = lane&15
  const int rb = lnk * 4;
  #pragma unroll
  for (int i = 0; i < 8; ++i) {
    #pragma unroll
    for (int ii = 0; ii < 4; ++ii) {
      long m = Arow0 + wrow * 128 + i * 16 + rb + ii;
      float* cp = C + m * (long)ldc + Brow0 + wcol * 64 + ln15;
      #pragma unroll
      for (int j = 0; j < 4; ++j) cp[j * 16] = acc[i][j][ii];
    }
  }
}

// ---------------------------------------------------------------------------
// 5) 128x128 GEMM (m97 structure) for PV; blockIdx.z = split-K chunk.
//    C is bf16 partials: C[m][n] (+)= sum_k A[m][k+z*zk]*B[n][k+z*zk].
__global__ __launch_bounds__(256) void gemm_pv_k(
    const unsigned short* __restrict__ A, const unsigned short* __restrict__ B,
    unsigned short* __restrict__ C, int K, int lda, int ldb, int ldc,
    long zk, long zc, int accumulate)
{
  A += (long)blockIdx.z * zk;
  B += (long)blockIdx.z * zk;
  C += (long)blockIdx.z * zc;
  __shared__ __align__(16) unsigned short As[128 * 32];
  __shared__ __align__(16) unsigned short Bs[128 * 32];
  const int tid = threadIdx.x;
  const int lane = tid & 63;
  const int wave = tid >> 6;
  const int wm = (wave >> 1) * 64;
  const int wn = (wave & 1) * 64;
  const long Arow0 = (long)blockIdx.x * 128;
  const long Brow0 = (long)blockIdx.y * 128;

  f32x4 acc[4][4] = {};
  const int r  = lane & 15;
  const int kb = (lane >> 4) * 8;

  for (int k0 = 0; k0 < K; k0 += 32) {
    #pragma unroll
    for (int pass = 0; pass < 2; ++pass) {
      const int chunk = pass * 4 + wave;
      const int m  = chunk * 16 + (lane >> 2);
      const int ke = (lane & 3) * 8;
      gload_lds16(A + (Arow0 + m) * (long)lda + k0 + ke, &As[chunk * 512 + lane * 8]);
      gload_lds16(B + (Brow0 + m) * (long)ldb + k0 + ke, &Bs[chunk * 512 + lane * 8]);
    }
    __syncthreads();

    bf16x8 af[4], bfr[4];
    #pragma unroll
    for (int f = 0; f < 4; ++f) {
      af[f]  = *(const bf16x8*)&As[(wm + f * 16 + r) * 32 + kb];
      bfr[f] = *(const bf16x8*)&Bs[(wn + f * 16 + r) * 32 + kb];
    }
    #pragma unroll
    for (int i = 0; i < 4; ++i)
      #pragma unroll
      for (int j = 0; j < 4; ++j)
        acc[i][j] = __builtin_amdgcn_mfma_f32_16x16x32_bf16(af[i], bfr[j], acc[i][j], 0, 0, 0);
    __syncthreads();
  }

  const int rb = (lane >> 4) * 4;
  const int cn = lane & 15;
  #pragma unroll
  for (int i = 0; i < 4; ++i) {
    #pragma unroll
    for (int ii = 0; ii < 4; ++ii) {
      long m = Arow0 + wm + i * 16 + rb + ii;
      unsigned short* cp = C + m * (long)ldc + Brow0 + wn + cn;
      #pragma unroll
      for (int j = 0; j < 4; ++j) {
        float v = acc[i][j][ii];
        if (accumulate) v += bf2f(cp[j * 16]);
        cp[j * 16] = f2bf(v);
      }
    }
  }
}

// ---------------------------------------------------------------------------
// 6) row softmax, in-place fp32 -> bf16 (row = 3840 fp32; PV lda = 7680)
__global__ __launch_bounds__(256) void softmax_rows_k(float* __restrict__ logits)
{
  const int q = blockIdx.x;
  float* row = logits + (size_t)q * 3840;
  unsigned short* orow = (unsigned short*)row;
  const int tid = threadIdx.x;
  float v[15];
  float mx = -1e30f;
  #pragma unroll
  for (int j = 0; j < 15; ++j) {
    int s = tid + j * 256;
    float x = (s < 3600) ? row[s] : -1e30f;
    v[j] = x;
    mx = fmaxf(mx, x);
  }
  #pragma unroll
  for (int o = 32; o > 0; o >>= 1) mx = fmaxf(mx, __shfl_xor(mx, o));
  __shared__ float wmax[4], wsum[4];
  if ((tid & 63) == 0) wmax[tid >> 6] = mx;
  __syncthreads();
  mx = fmaxf(fmaxf(wmax[0], wmax[1]), fmaxf(wmax[2], wmax[3]));
  float sum = 0.f;
  #pragma unroll
  for (int j = 0; j < 15; ++j) {
    int s = tid + j * 256;
    float e = (s < 3600) ? __expf(v[j] - mx) : 0.f;
    v[j] = e;
    sum += e;
  }
  #pragma unroll
  for (int o = 32; o > 0; o >>= 1) sum += __shfl_xor(sum, o);
  if ((tid & 63) == 0) wsum[tid >> 6] = sum;
  __syncthreads();
  sum = wsum[0] + wsum[1] + wsum[2] + wsum[3];
  const float inv = 1.0f / sum;
  #pragma unroll
  for (int j = 0; j < 15; ++j) {
    int s = tid + j * 256;
    orow[s] = (s < 3600) ? f2bf(v[j] * inv) : (unsigned short)0;
  }
}

// ---------------------------------------------------------------------------
// 7) out[c][p] = 0.5*f_q[c][p] + 0.25*sum_z P[z][p][c]   (bf16 partials)
__global__ __launch_bounds__(256) void final_blend_k(
    const unsigned short* __restrict__ P, const float* __restrict__ fq,
    float* __restrict__ out)
{
  __shared__ float t[32][33];
  const int tx = threadIdx.x, ty = threadIdx.y;
  const int p0 = blockIdx.x * 32, c0 = blockIdx.y * 32;
  const long ZC = 3840L * 512;
  #pragma unroll
  for (int i = 0; i < 4; ++i) {
    int p = p0 + ty + i * 8, c = c0 + tx;
    float s = 0.f;
    if (p < 3600) {
      size_t o = (size_t)p * 512 + c;
      #pragma unroll
      for (int z = 0; z < 6; ++z) s += bf2f(P[o + (size_t)z * ZC]);
    }
    t[ty + i * 8][tx] = s;
  }
  __syncthreads();
  #pragma unroll
  for (int i = 0; i < 4; ++i) {
    int c = c0 + ty + i * 8, p = p0 + tx;
    if (p < 3600) {
      size_t o = (size_t)c * 3600 + p;
      out[o] = 0.5f * fq[o] + 0.25f * t[tx][ty + i * 8];
    }
  }
}

// ---------------------------------------------------------------------------
extern "C" void kernel_launch(void* const* d_in, const int* in_sizes, int n_in,
                              void* d_out, int out_size, void* d_ws, size_t ws_size,
                              hipStream_t stream) {
  const float* fq3 = (const float*)d_in[0];
  const float* fq4 = (const float*)d_in[1];
  const float* fs3 = (const float*)d_in[2];
  const float* fs4 = (const float*)d_in[3];
  const float* f_q = (const float*)d_in[4];
  const float* f_s = (const float*)d_in[5];
  const float* wch = (const float*)d_in[6];
  float* out = (float*)d_out;

  const size_t HW = 3600, MP = 3840, KC = 3072, CH = 512;

  // workspace (~134 MB)
  unsigned short* QT = (unsigned short*)d_ws;    // (MP, KC) bf16, query (TEMP*w folded)
  unsigned short* ST = QT + MP * KC;             // (MP, KC) bf16, support (per batch)
  unsigned short* V  = ST + MP * KC;             // (CH, MP) bf16 (per batch)
  float* logits = (float*)(V + CH * MP);         // (MP, MP) fp32; softmax -> bf16 in place
  unsigned short* Pb = (unsigned short*)(logits + MP * MP);  // 6 x (MP, CH) bf16 partials
  float* invn = (float*)(Pb + 6 * MP * CH);      // 6 x 3600
  float* part = logits;                          // norm scratch (consumed pre-GEMM)

  hipMemsetAsync(QT + HW * KC, 0, (MP - HW) * KC * 2, stream);
  hipMemsetAsync(ST + HW * KC, 0, (MP - HW) * KC * 2, stream);
  hipMemsetAsync(V, 0, CH * MP * 2, stream);

  Src6 S;
  S.p[0] = fq4; S.p[1] = fs4; S.p[2] = fs4 + 2048 * HW;
  S.p[3] = fq3; S.p[4] = fs3; S.p[5] = fs3 + 1024 * HW;
  colnorm_part6_k<<<dim3(57, 16, 6), 256, 0, stream>>>(S, part);
  colnorm_fin6_k<<<dim3(15, 6), 256, 0, stream>>>(part, invn);

  dim3 tb(32, 8);
  tpose2_k<<<dim3(113, 96), tb, 0, stream>>>(fq4, fq3, invn + 0 * HW, invn + 3 * HW,
                                             wch, 1, QT);

  for (int b = 0; b < 2; ++b) {
    castv_k<<<7200, 256, 0, stream>>>(f_s + (size_t)b * CH * HW, V);
    tpose2_k<<<dim3(113, 96), tb, 0, stream>>>(
        fs4 + (size_t)b * 2048 * HW, fs3 + (size_t)b * 1024 * HW,
        invn + (1 + b) * HW, invn + (4 + b) * HW, wch, 0, ST);

    gemm256_k<<<225, 512, 0, stream>>>(QT, ST, logits, 3072, 3072, 3072, 3840, 15);

    softmax_rows_k<<<3600, 256, 0, stream>>>(logits);

    // PV split-K=6, bf16 partials
    gemm_pv_k<<<dim3(30, 4, 6), 256, 0, stream>>>(
        (const unsigned short*)logits, V, Pb, 640, 7680, 3840, 512,
        640L, 3840L * 512, b);
  }

  final_blend_k<<<dim3(113, 16), tb, 0, stream>>>(Pb, f_q, out);
}

// Round 8
// 339.607 us; speedup vs baseline: 1.3079x; 1.2700x over previous
//
#include <hip/hip_runtime.h>
#include <cstdint>

#define TEMP_C 20.0f

typedef float f32x4 __attribute__((ext_vector_type(4)));
typedef float f32x16 __attribute__((ext_vector_type(16)));
typedef __bf16 bf16x8 __attribute__((ext_vector_type(8)));
typedef int i32x4 __attribute__((ext_vector_type(4)));
typedef int i32x8 __attribute__((ext_vector_type(8)));

// fp32 -> bf16 round-to-nearest-even
__device__ __forceinline__ unsigned short f2bf(float f) {
  union { float f; unsigned int u; } v; v.f = f;
  unsigned int r = v.u + 0x7FFFu + ((v.u >> 16) & 1u);
  return (unsigned short)(r >> 16);
}
__device__ __forceinline__ float bf2f(unsigned short b) {
  union { unsigned int u; float f; } v; v.u = ((unsigned int)b) << 16;
  return v.f;
}

// fp32 -> OCP e4m3fn, RTNE, clamp to +-448
__device__ __forceinline__ unsigned char f2e4m3(float f) {
  unsigned u = __float_as_uint(f);
  unsigned s = (u >> 24) & 0x80u;
  float a = fminf(fabsf(f), 448.0f);
  if (a < 0.015625f) {                       // denormal range (incl. round-up to 2^-6)
    int d = (int)rintf(a * 512.0f);          // 0..8 ; byte 8 == 2^-6 (first normal)
    return (unsigned char)(s | (unsigned)d);
  }
  unsigned au = __float_as_uint(a);
  unsigned r = au + 0xFFFFFu + ((au >> 20) & 1u);   // RTNE at 3 mantissa bits
  int Ep = (int)(r >> 23) - 127;
  if (Ep > 8) return (unsigned char)(s | 0x7E);     // clamp 448
  unsigned m = (r >> 20) & 7u;
  return (unsigned char)(s | ((unsigned)(Ep + 7) << 3) | m);
}

// async global->LDS, 16B per lane (dest = wave-uniform base + lane*16)
__device__ __forceinline__ void gload_lds16(const void* g, void* l) {
  __builtin_amdgcn_global_load_lds(
      (__attribute__((address_space(1))) void*)(g),
      (__attribute__((address_space(3))) void*)(l), 16, 0, 0);
}

// ---------------------------------------------------------------------------
// 1a) partial sum-of-squares, all 6 feature slices in one launch.
struct Src6 { const float* p[6]; };

__global__ __launch_bounds__(256) void colnorm_part6_k(
    Src6 S, float* __restrict__ part)
{
  const int sl = blockIdx.z;
  const float* __restrict__ X = S.p[sl];
  const int C = (sl < 3) ? 2048 : 1024;
  const int cpc = C >> 4;
  __shared__ float red[4][64];
  const int pix = threadIdx.x & 63;
  const int sub = threadIdx.x >> 6;
  const int p = blockIdx.x * 64 + pix;
  const int c0 = blockIdx.y * cpc;
  float s = 0.f;
  if (p < 3600) {
    for (int c = c0 + sub; c < c0 + cpc; c += 4) {
      float v = X[(size_t)c * 3600 + p];
      s += v * v;
    }
  }
  red[sub][pix] = s;
  __syncthreads();
  if (sub == 0 && p < 3600) {
    part[(size_t)(sl * 16 + blockIdx.y) * 3600 + p] =
        red[0][pix] + red[1][pix] + red[2][pix] + red[3][pix];
  }
}

// 1b) finish all 6 slices
__global__ __launch_bounds__(256) void colnorm_fin6_k(
    const float* __restrict__ part, float* __restrict__ invn)
{
  const int z = blockIdx.y;
  const int p = blockIdx.x * 256 + threadIdx.x;
  if (p >= 3600) return;
  float s = 0.f;
  #pragma unroll
  for (int j = 0; j < 16; ++j) s += part[(size_t)(z * 16 + j) * 3600 + p];
  invn[(size_t)z * 3600 + p] = 1.0f / fmaxf(sqrtf(s), 1e-12f);
}

// ---------------------------------------------------------------------------
// 2) fused transpose+scale+FP8 cast for BOTH pyramid levels of one feature set.
//    query side: mult = TEMP*w/4 ; support side: mult = 4  (product = TEMP*w)
__global__ __launch_bounds__(256) void tpose2_f8_k(
    const float* __restrict__ X4, const float* __restrict__ X3,
    const float* __restrict__ i4, const float* __restrict__ i3,
    const float* __restrict__ wch, int usew, unsigned char* __restrict__ T)
{
  __shared__ float tile[32][33];
  const int tx = threadIdx.x, ty = threadIdx.y;
  const int y = blockIdx.y;
  const float* X; const float* inv; int c0, cdst; float mult;
  if (y < 64) { X = X4; inv = i4; c0 = y * 32;        cdst = c0;        mult = usew ? TEMP_C * wch[0] * 0.25f : 4.0f; }
  else        { X = X3; inv = i3; c0 = (y - 64) * 32; cdst = 2048 + c0; mult = usew ? TEMP_C * wch[1] * 0.25f : 4.0f; }
  const int p0 = blockIdx.x * 32;
  #pragma unroll
  for (int i = 0; i < 4; ++i) {
    int c = c0 + ty + i * 8, p = p0 + tx;
    tile[ty + i * 8][tx] = (p < 3600) ? X[(size_t)c * 3600 + p] : 0.f;
  }
  __syncthreads();
  #pragma unroll
  for (int i = 0; i < 4; ++i) {
    int p = p0 + ty + i * 8;
    if (p < 3600) {
      float sc = inv[p] * mult;
      T[(size_t)p * 3072 + cdst + tx] = f2e4m3(tile[tx][ty + i * 8] * sc);
    }
  }
}

// ---------------------------------------------------------------------------
// 3) V cast: f_s slice (512, 3600) fp32 -> V (512, 3840) bf16 (pad pre-zeroed)
__global__ void castv_k(const float* __restrict__ X, unsigned short* __restrict__ V)
{
  int i = blockIdx.x * 256 + threadIdx.x;
  if (i >= 512 * 3600) return;
  int c = i / 3600, s = i - c * 3600;
  V[(size_t)c * 3840 + s] = f2bf(X[i]);
}

// ---------------------------------------------------------------------------
// 4) 256x256 MX-fp8 GEMM (mfma_scale_f32_32x32x64_f8f6f4, unit scales).
//    C[m][n] = sum_k A[m][k]*B[n][k], fp8 e4m3 in / fp32 out. BK=128, 2 LDS
//    slots (128KiB), 2 barriers/tile:
//      STAGE(t+1 -> other slot); vmcnt(8) [counted: waits tile t only];
//      s_barrier; 4 sub-phases of ds_read->mfma (compiler-scheduled lgkmcnt,
//      waves drift into read/MFMA anti-phase); s_barrier.
//    XOR swizzle on 128B rows: 16B-group g stored at g^(row&7) — geometry
//    measured 0 conflicts in rounds 4-7. Linear LDS dest, inverse-swizzled
//    global src, swizzled reads (rule #21).
__global__ __launch_bounds__(512, 2) void gemm256_f8(
    const unsigned char* __restrict__ A, const unsigned char* __restrict__ B,
    float* __restrict__ C, int K, int lda, int ldb, int ldc, int nbn)
{
  __shared__ __align__(16) unsigned char As[2][256 * 128];
  __shared__ __align__(16) unsigned char Bs[2][256 * 128];

  const int tid  = threadIdx.x;
  const int lane = tid & 63;
  const int wave = tid >> 6;
  const int wrow = wave >> 2;   // 0..1 (M half)
  const int wcol = wave & 3;    // 0..3 (N quarter)

  // XCD-aware bijective block remap (m204)
  const int nwg = gridDim.x;
  const int q8 = nwg >> 3, r8 = nwg & 7;
  const int xcd = blockIdx.x & 7, bidx = blockIdx.x >> 3;
  const int wg = (xcd < r8 ? xcd * (q8 + 1) : r8 * (q8 + 1) + (xcd - r8) * q8) + bidx;
  const long Arow0 = (long)(wg / nbn) * 256;
  const long Brow0 = (long)(wg % nbn) * 256;

  // staging: 2048 chunks of 16B per operand per slot; thread owns q*512+tid.
  // chunk c <-> (row=c>>3, g'=c&7); global g = g'^(row&7); LDS dest linear c*16.
  const unsigned char* sA[4];
  const unsigned char* sB[4];
  #pragma unroll
  for (int q = 0; q < 4; ++q) {
    const int c = q * 512 + tid;
    const int row = c >> 3;
    const int g = (c & 7) ^ (row & 7);
    sA[q] = A + (Arow0 + row) * (long)lda + g * 16;
    sB[q] = B + (Brow0 + row) * (long)ldb + g * 16;
  }

  #define STAGE(tt) do {                                        \
    const long _ko = (long)(tt) * 128; const int _sl = (tt) & 1; \
    _Pragma("unroll")                                           \
    for (int q = 0; q < 4; ++q)                                 \
      gload_lds16(sA[q] + _ko, &As[_sl][(q * 512 + tid) * 16]); \
    _Pragma("unroll")                                           \
    for (int q = 0; q < 4; ++q)                                 \
      gload_lds16(sB[q] + _ko, &Bs[_sl][(q * 512 + tid) * 16]); \
  } while (0)

  const int l31 = lane & 31, lk = lane >> 5, rx = l31 & 7;
  // A frag (mtile m 0..3, khalf h): row = wrow*128+m*32+l31, 32B at
  // kbyte = h*64+lk*32 (+16); swizzled 16B-group (h*4+lk*2+s)^rx.
  int abase[4], bbase[2];
  #pragma unroll
  for (int m = 0; m < 4; ++m) abase[m] = (wrow * 128 + m * 32 + l31) * 128;
  #pragma unroll
  for (int n = 0; n < 2; ++n) bbase[n] = (wcol * 64 + n * 32 + l31) * 128;

  f32x16 acc[4][2] = {};
  const int NT = K >> 7;   // 128-wide K-tiles (24)

  STAGE(0);

  for (int t = 0; t < NT; ++t) {
    const int sl = t & 1;
    if (t + 1 < NT) {
      STAGE(t + 1);                                     // -> slot sl^1 (freed by prev tile's end barrier)
      asm volatile("s_waitcnt vmcnt(8)" ::: "memory");  // tile t landed; t+1's 8 in flight
    } else {
      asm volatile("s_waitcnt vmcnt(0)" ::: "memory");
    }
    asm volatile("s_barrier" ::: "memory");             // slot sl visible to all waves

    const unsigned char* Ap = As[sl];
    const unsigned char* Bp = Bs[sl];
    #define LDF(base, h, s) (*(const i32x4*)((base) + ((((h) * 4 + lk * 2 + (s)) ^ rx) << 4)))
    #define FRAG(dst, base, h) do {                     \
      i32x4 _lo = LDF(base, h, 0);                      \
      i32x4 _hi = LDF(base, h, 1);                      \
      dst[0]=_lo[0]; dst[1]=_lo[1]; dst[2]=_lo[2]; dst[3]=_lo[3]; \
      dst[4]=_hi[0]; dst[5]=_hi[1]; dst[6]=_hi[2]; dst[7]=_hi[3]; \
    } while (0)
    #define MFMA8(a, b, m, n) \
      acc[m][n] = __builtin_amdgcn_mfma_scale_f32_32x32x64_f8f6f4( \
          a, b, acc[m][n], 0, 0, 0, 127, 0, 127)

    #pragma unroll
    for (int h = 0; h < 2; ++h) {
      i32x8 b0, b1, a0, a1;
      FRAG(b0, Bp + bbase[0], h); FRAG(b1, Bp + bbase[1], h);
      FRAG(a0, Ap + abase[0], h); FRAG(a1, Ap + abase[1], h);
      __builtin_amdgcn_s_setprio(1);
      MFMA8(a0, b0, 0, 0); MFMA8(a0, b1, 0, 1);
      MFMA8(a1, b0, 1, 0); MFMA8(a1, b1, 1, 1);
      __builtin_amdgcn_s_setprio(0);
      FRAG(a0, Ap + abase[2], h); FRAG(a1, Ap + abase[3], h);
      __builtin_amdgcn_s_setprio(1);
      MFMA8(a0, b0, 2, 0); MFMA8(a0, b1, 2, 1);
      MFMA8(a1, b0, 3, 0); MFMA8(a1, b1, 3, 1);
      __builtin_amdgcn_s_setprio(0);
    }
    #undef LDF
    #undef FRAG
    #undef MFMA8
    asm volatile("s_barrier" ::: "memory");             // all reads of slot sl done
  }
  #undef STAGE

  // epilogue: 32x32 C/D layout (m74/m101): col=lane&31,
  // row = (reg&3) + 8*(reg>>2) + 4*(lane>>5)
  #pragma unroll
  for (int m = 0; m < 4; ++m) {
    const long rowb = Arow0 + wrow * 128 + m * 32;
    #pragma unroll
    for (int g4 = 0; g4 < 4; ++g4) {
      #pragma unroll
      for (int r4 = 0; r4 < 4; ++r4) {
        const long row = rowb + r4 + 8 * g4 + 4 * lk;
        float* cp = C + row * (long)ldc + Brow0 + wcol * 64 + l31;
        cp[0]  = acc[m][0][g4 * 4 + r4];
        cp[32] = acc[m][1][g4 * 4 + r4];
      }
    }
  }
}

// ---------------------------------------------------------------------------
// 5) 128x128 GEMM (m97 structure) for PV; blockIdx.z = split-K chunk.
//    C is bf16 partials: C[m][n] (+)= sum_k A[m][k+z*zk]*B[n][k+z*zk].
__global__ __launch_bounds__(256) void gemm_pv_k(
    const unsigned short* __restrict__ A, const unsigned short* __restrict__ B,
    unsigned short* __restrict__ C, int K, int lda, int ldb, int ldc,
    long zk, long zc, int accumulate)
{
  A += (long)blockIdx.z * zk;
  B += (long)blockIdx.z * zk;
  C += (long)blockIdx.z * zc;
  __shared__ __align__(16) unsigned short As[128 * 32];
  __shared__ __align__(16) unsigned short Bs[128 * 32];
  const int tid = threadIdx.x;
  const int lane = tid & 63;
  const int wave = tid >> 6;
  const int wm = (wave >> 1) * 64;
  const int wn = (wave & 1) * 64;
  const long Arow0 = (long)blockIdx.x * 128;
  const long Brow0 = (long)blockIdx.y * 128;

  f32x4 acc[4][4] = {};
  const int r  = lane & 15;
  const int kb = (lane >> 4) * 8;

  for (int k0 = 0; k0 < K; k0 += 32) {
    #pragma unroll
    for (int pass = 0; pass < 2; ++pass) {
      const int chunk = pass * 4 + wave;
      const int m  = chunk * 16 + (lane >> 2);
      const int ke = (lane & 3) * 8;
      gload_lds16(A + (Arow0 + m) * (long)lda + k0 + ke, &As[chunk * 512 + lane * 8]);
      gload_lds16(B + (Brow0 + m) * (long)ldb + k0 + ke, &Bs[chunk * 512 + lane * 8]);
    }
    __syncthreads();

    bf16x8 af[4], bfr[4];
    #pragma unroll
    for (int f = 0; f < 4; ++f) {
      af[f]  = *(const bf16x8*)&As[(wm + f * 16 + r) * 32 + kb];
      bfr[f] = *(const bf16x8*)&Bs[(wn + f * 16 + r) * 32 + kb];
    }
    #pragma unroll
    for (int i = 0; i < 4; ++i)
      #pragma unroll
      for (int j = 0; j < 4; ++j)
        acc[i][j] = __builtin_amdgcn_mfma_f32_16x16x32_bf16(af[i], bfr[j], acc[i][j], 0, 0, 0);
    __syncthreads();
  }

  const int rb = (lane >> 4) * 4;
  const int cn = lane & 15;
  #pragma unroll
  for (int i = 0; i < 4; ++i) {
    #pragma unroll
    for (int ii = 0; ii < 4; ++ii) {
      long m = Arow0 + wm + i * 16 + rb + ii;
      unsigned short* cp = C + m * (long)ldc + Brow0 + wn + cn;
      #pragma unroll
      for (int j = 0; j < 4; ++j) {
        float v = acc[i][j][ii];
        if (accumulate) v += bf2f(cp[j * 16]);
        cp[j * 16] = f2bf(v);
      }
    }
  }
}

// ---------------------------------------------------------------------------
// 6) row softmax, in-place fp32 -> bf16 (row = 3840 fp32; PV lda = 7680)
__global__ __launch_bounds__(256) void softmax_rows_k(float* __restrict__ logits)
{
  const int q = blockIdx.x;
  float* row = logits + (size_t)q * 3840;
  unsigned short* orow = (unsigned short*)row;
  const int tid = threadIdx.x;
  float v[15];
  float mx = -1e30f;
  #pragma unroll
  for (int j = 0; j < 15; ++j) {
    int s = tid + j * 256;
    float x = (s < 3600) ? row[s] : -1e30f;
    v[j] = x;
    mx = fmaxf(mx, x);
  }
  #pragma unroll
  for (int o = 32; o > 0; o >>= 1) mx = fmaxf(mx, __shfl_xor(mx, o));
  __shared__ float wmax[4], wsum[4];
  if ((tid & 63) == 0) wmax[tid >> 6] = mx;
  __syncthreads();
  mx = fmaxf(fmaxf(wmax[0], wmax[1]), fmaxf(wmax[2], wmax[3]));
  float sum = 0.f;
  #pragma unroll
  for (int j = 0; j < 15; ++j) {
    int s = tid + j * 256;
    float e = (s < 3600) ? __expf(v[j] - mx) : 0.f;
    v[j] = e;
    sum += e;
  }
  #pragma unroll
  for (int o = 32; o > 0; o >>= 1) sum += __shfl_xor(sum, o);
  if ((tid & 63) == 0) wsum[tid >> 6] = sum;
  __syncthreads();
  sum = wsum[0] + wsum[1] + wsum[2] + wsum[3];
  const float inv = 1.0f / sum;
  #pragma unroll
  for (int j = 0; j < 15; ++j) {
    int s = tid + j * 256;
    orow[s] = (s < 3600) ? f2bf(v[j] * inv) : (unsigned short)0;
  }
}

// ---------------------------------------------------------------------------
// 7) out[c][p] = 0.5*f_q[c][p] + 0.25*sum_z P[z][p][c]   (bf16 partials)
__global__ __launch_bounds__(256) void final_blend_k(
    const unsigned short* __restrict__ P, const float* __restrict__ fq,
    float* __restrict__ out)
{
  __shared__ float t[32][33];
  const int tx = threadIdx.x, ty = threadIdx.y;
  const int p0 = blockIdx.x * 32, c0 = blockIdx.y * 32;
  const long ZC = 3840L * 512;
  #pragma unroll
  for (int i = 0; i < 4; ++i) {
    int p = p0 + ty + i * 8, c = c0 + tx;
    float s = 0.f;
    if (p < 3600) {
      size_t o = (size_t)p * 512 + c;
      #pragma unroll
      for (int z = 0; z < 6; ++z) s += bf2f(P[o + (size_t)z * ZC]);
    }
    t[ty + i * 8][tx] = s;
  }
  __syncthreads();
  #pragma unroll
  for (int i = 0; i < 4; ++i) {
    int c = c0 + ty + i * 8, p = p0 + tx;
    if (p < 3600) {
      size_t o = (size_t)c * 3600 + p;
      out[o] = 0.5f * fq[o] + 0.25f * t[tx][ty + i * 8];
    }
  }
}

// ---------------------------------------------------------------------------
extern "C" void kernel_launch(void* const* d_in, const int* in_sizes, int n_in,
                              void* d_out, int out_size, void* d_ws, size_t ws_size,
                              hipStream_t stream) {
  const float* fq3 = (const float*)d_in[0];
  const float* fq4 = (const float*)d_in[1];
  const float* fs3 = (const float*)d_in[2];
  const float* fs4 = (const float*)d_in[3];
  const float* f_q = (const float*)d_in[4];
  const float* f_s = (const float*)d_in[5];
  const float* wch = (const float*)d_in[6];
  float* out = (float*)d_out;

  const size_t HW = 3600, MP = 3840, KC = 3072, CH = 512;

  // workspace (~110 MB)
  unsigned char* QT8 = (unsigned char*)d_ws;         // (MP, KC) fp8 query (20w/4 folded)
  unsigned char* ST8 = QT8 + MP * KC;                // (MP, KC) fp8 support (x4 folded)
  unsigned short* V  = (unsigned short*)(ST8 + MP * KC);  // (CH, MP) bf16
  float* logits = (float*)(V + CH * MP);             // (MP, MP) fp32; softmax -> bf16 in place
  unsigned short* Pb = (unsigned short*)(logits + MP * MP);  // 6 x (MP, CH) bf16 partials
  float* invn = (float*)(Pb + 6 * MP * CH);          // 6 x 3600
  float* part = logits;                              // norm scratch (consumed pre-GEMM)

  hipMemsetAsync(QT8 + HW * KC, 0, (MP - HW) * KC, stream);
  hipMemsetAsync(ST8 + HW * KC, 0, (MP - HW) * KC, stream);
  hipMemsetAsync(V, 0, CH * MP * 2, stream);

  Src6 S;
  S.p[0] = fq4; S.p[1] = fs4; S.p[2] = fs4 + 2048 * HW;
  S.p[3] = fq3; S.p[4] = fs3; S.p[5] = fs3 + 1024 * HW;
  colnorm_part6_k<<<dim3(57, 16, 6), 256, 0, stream>>>(S, part);
  colnorm_fin6_k<<<dim3(15, 6), 256, 0, stream>>>(part, invn);

  dim3 tb(32, 8);
  tpose2_f8_k<<<dim3(113, 96), tb, 0, stream>>>(fq4, fq3, invn + 0 * HW, invn + 3 * HW,
                                                wch, 1, QT8);

  for (int b = 0; b < 2; ++b) {
    castv_k<<<7200, 256, 0, stream>>>(f_s + (size_t)b * CH * HW, V);
    tpose2_f8_k<<<dim3(113, 96), tb, 0, stream>>>(
        fs4 + (size_t)b * 2048 * HW, fs3 + (size_t)b * 1024 * HW,
        invn + (1 + b) * HW, invn + (4 + b) * HW, wch, 0, ST8);

    // logits[q][s] = sum_k QT8[q][k]*ST8[s][k] (MX-fp8, unit scales)
    gemm256_f8<<<225, 512, 0, stream>>>(QT8, ST8, logits, 3072, 3072, 3072, 3840, 15);

    softmax_rows_k<<<3600, 256, 0, stream>>>(logits);

    // PV split-K=6, bf16 partials
    gemm_pv_k<<<dim3(30, 4, 6), 256, 0, stream>>>(
        (const unsigned short*)logits, V, Pb, 640, 7680, 3840, 512,
        640L, 3840L * 512, b);
  }

  final_blend_k<<<dim3(113, 16), tb, 0, stream>>>(Pb, f_q, out);
}

// Round 9
// 332.699 us; speedup vs baseline: 1.3351x; 1.0208x over previous
//
#include <hip/hip_runtime.h>
#include <cstdint>

#define TEMP_C 20.0f

typedef float f32x4 __attribute__((ext_vector_type(4)));
typedef float f32x16 __attribute__((ext_vector_type(16)));
typedef __bf16 bf16x8 __attribute__((ext_vector_type(8)));
typedef int i32x4 __attribute__((ext_vector_type(4)));
typedef int i32x8 __attribute__((ext_vector_type(8)));

// fp32 -> bf16 round-to-nearest-even
__device__ __forceinline__ unsigned short f2bf(float f) {
  union { float f; unsigned int u; } v; v.f = f;
  unsigned int r = v.u + 0x7FFFu + ((v.u >> 16) & 1u);
  return (unsigned short)(r >> 16);
}
__device__ __forceinline__ float bf2f(unsigned short b) {
  union { unsigned int u; float f; } v; v.u = ((unsigned int)b) << 16;
  return v.f;
}

// fp32 -> OCP e4m3fn, RTNE, clamp to +-448
__device__ __forceinline__ unsigned char f2e4m3(float f) {
  unsigned u = __float_as_uint(f);
  unsigned s = (u >> 24) & 0x80u;
  float a = fminf(fabsf(f), 448.0f);
  if (a < 0.015625f) {
    int d = (int)rintf(a * 512.0f);
    return (unsigned char)(s | (unsigned)d);
  }
  unsigned au = __float_as_uint(a);
  unsigned r = au + 0xFFFFFu + ((au >> 20) & 1u);
  int Ep = (int)(r >> 23) - 127;
  if (Ep > 8) return (unsigned char)(s | 0x7E);
  unsigned m = (r >> 20) & 7u;
  return (unsigned char)(s | ((unsigned)(Ep + 7) << 3) | m);
}

// async global->LDS, 16B per lane (dest = wave-uniform base + lane*16)
__device__ __forceinline__ void gload_lds16(const void* g, void* l) {
  __builtin_amdgcn_global_load_lds(
      (__attribute__((address_space(1))) void*)(g),
      (__attribute__((address_space(3))) void*)(l), 16, 0, 0);
}

// ---------------------------------------------------------------------------
// 1a) partial sum-of-squares, all 6 feature slices in one launch.
struct Src6 { const float* p[6]; };

__global__ __launch_bounds__(256) void colnorm_part6_k(
    Src6 S, float* __restrict__ part)
{
  const int sl = blockIdx.z;
  const float* __restrict__ X = S.p[sl];
  const int C = (sl < 3) ? 2048 : 1024;
  const int cpc = C >> 4;
  __shared__ float red[4][64];
  const int pix = threadIdx.x & 63;
  const int sub = threadIdx.x >> 6;
  const int p = blockIdx.x * 64 + pix;
  const int c0 = blockIdx.y * cpc;
  float s = 0.f;
  if (p < 3600) {
    for (int c = c0 + sub; c < c0 + cpc; c += 4) {
      float v = X[(size_t)c * 3600 + p];
      s += v * v;
    }
  }
  red[sub][pix] = s;
  __syncthreads();
  if (sub == 0 && p < 3600) {
    part[(size_t)(sl * 16 + blockIdx.y) * 3600 + p] =
        red[0][pix] + red[1][pix] + red[2][pix] + red[3][pix];
  }
}

// 1b) finish all 6 slices
__global__ __launch_bounds__(256) void colnorm_fin6_k(
    const float* __restrict__ part, float* __restrict__ invn)
{
  const int z = blockIdx.y;
  const int p = blockIdx.x * 256 + threadIdx.x;
  if (p >= 3600) return;
  float s = 0.f;
  #pragma unroll
  for (int j = 0; j < 16; ++j) s += part[(size_t)(z * 16 + j) * 3600 + p];
  invn[(size_t)z * 3600 + p] = 1.0f / fmaxf(sqrtf(s), 1e-12f);
}

// ---------------------------------------------------------------------------
// 2) fused transpose+scale+FP8 cast, writing K-GROUP-MAJOR layout:
//    T[(g*3840 + p)*16 + b] where col = g*16+b, col = cdst+tx.
//    query side: mult = TEMP*w/4 ; support side: mult = 4  (product = TEMP*w)
__global__ __launch_bounds__(256) void tpose2_f8_k(
    const float* __restrict__ X4, const float* __restrict__ X3,
    const float* __restrict__ i4, const float* __restrict__ i3,
    const float* __restrict__ wch, int usew, unsigned char* __restrict__ T)
{
  __shared__ float tile[32][33];
  const int tx = threadIdx.x, ty = threadIdx.y;
  const int y = blockIdx.y;
  const float* X; const float* inv; int c0, cdst; float mult;
  if (y < 64) { X = X4; inv = i4; c0 = y * 32;        cdst = c0;        mult = usew ? TEMP_C * wch[0] * 0.25f : 4.0f; }
  else        { X = X3; inv = i3; c0 = (y - 64) * 32; cdst = 2048 + c0; mult = usew ? TEMP_C * wch[1] * 0.25f : 4.0f; }
  const int p0 = blockIdx.x * 32;
  #pragma unroll
  for (int i = 0; i < 4; ++i) {
    int c = c0 + ty + i * 8, p = p0 + tx;
    tile[ty + i * 8][tx] = (p < 3600) ? X[(size_t)c * 3600 + p] : 0.f;
  }
  __syncthreads();
  const int col = cdst + tx;
  const size_t gbase = (size_t)(col >> 4) * 3840 * 16 + (col & 15);
  #pragma unroll
  for (int i = 0; i < 4; ++i) {
    int p = p0 + ty + i * 8;
    if (p < 3600) {
      float sc = inv[p] * mult;
      T[gbase + (size_t)p * 16] = f2e4m3(tile[tx][ty + i * 8] * sc);
    }
  }
}

// ---------------------------------------------------------------------------
// 3) V cast: f_s slice (512, 3600) fp32 -> V (512, 3840) bf16 (pad pre-zeroed)
__global__ void castv_k(const float* __restrict__ X, unsigned short* __restrict__ V)
{
  int i = blockIdx.x * 256 + threadIdx.x;
  if (i >= 512 * 3600) return;
  int c = i / 3600, s = i - c * 3600;
  V[(size_t)c * 3840 + s] = f2bf(X[i]);
}

// ---------------------------------------------------------------------------
// 4) 256x256 MX-fp8 GEMM (mfma_scale_f32_32x32x64_f8f6f4, unit scales).
//    Operands in K-GROUP-MAJOR layout: chunk(g, p) at (g*MP + p)*16.
//    LDS [2 slots][8 groups][256 rows][16B] = 32KB/operand/slot:
//      - staging: thread c stages LDS slot c (linear, gload_lds-compatible)
//        from global ((t*8 + c>>8)*MP + row0 + (c&255))*16 — fully coalesced.
//      - frag read: (g*256 + row)*16 — 32 lanes contiguous 512B, 64 lanes
//        2x512B => every bank exactly 8 words = structural floor, 0 conflicts.
//    Schedule (round 8, verified): STAGE(t+1); counted vmcnt(8); s_barrier;
//    interleaved frag-reads + setprio-MFMA clusters (compiler lgkm); s_barrier.
__global__ __launch_bounds__(512, 2) void gemm256_f8(
    const unsigned char* __restrict__ A, const unsigned char* __restrict__ B,
    float* __restrict__ C, int K, int MPr, int ldc, int nbn)
{
  __shared__ __align__(16) unsigned char As[2][256 * 128];
  __shared__ __align__(16) unsigned char Bs[2][256 * 128];

  const int tid  = threadIdx.x;
  const int lane = tid & 63;
  const int wave = tid >> 6;
  const int wrow = wave >> 2;   // 0..1 (M half)
  const int wcol = wave & 3;    // 0..3 (N quarter)

  // XCD-aware bijective block remap (m204)
  const int nwg = gridDim.x;
  const int q8 = nwg >> 3, r8 = nwg & 7;
  const int xcd = blockIdx.x & 7, bidx = blockIdx.x >> 3;
  const int wg = (xcd < r8 ? xcd * (q8 + 1) : r8 * (q8 + 1) + (xcd - r8) * q8) + bidx;
  const long Arow0 = (long)(wg / nbn) * 256;
  const long Brow0 = (long)(wg % nbn) * 256;

  // staging sources: thread owns chunks c = q*512+tid; g = c>>8, r = c&255
  const unsigned char* sA[4];
  const unsigned char* sB[4];
  #pragma unroll
  for (int q = 0; q < 4; ++q) {
    const int c = q * 512 + tid;
    sA[q] = A + ((long)(c >> 8) * MPr + Arow0 + (c & 255)) * 16;
    sB[q] = B + ((long)(c >> 8) * MPr + Brow0 + (c & 255)) * 16;
  }
  const long kstride = (long)MPr * 16 * 8;   // 8 groups per K-tile

  #define STAGE(tt) do {                                        \
    const long _ko = (long)(tt) * kstride; const int _sl = (tt) & 1; \
    _Pragma("unroll")                                           \
    for (int q = 0; q < 4; ++q)                                 \
      gload_lds16(sA[q] + _ko, &As[_sl][(q * 512 + tid) * 16]); \
    _Pragma("unroll")                                           \
    for (int q = 0; q < 4; ++q)                                 \
      gload_lds16(sB[q] + _ko, &Bs[_sl][(q * 512 + tid) * 16]); \
  } while (0)

  const int l31 = lane & 31, lk = lane >> 5;
  int arow[4], brow[2];
  #pragma unroll
  for (int m = 0; m < 4; ++m) arow[m] = (wrow * 128 + m * 32 + l31) * 16;
  #pragma unroll
  for (int n = 0; n < 2; ++n) brow[n] = (wcol * 64 + n * 32 + l31) * 16;
  const int kq = (lk * 2) << 12;   // lane's k-group pair base (group stride 4096B)

  f32x16 acc[4][2] = {};
  const int NT = K >> 7;   // 128-wide K-tiles (24)

  STAGE(0);

  for (int t = 0; t < NT; ++t) {
    const int sl = t & 1;
    if (t + 1 < NT) {
      STAGE(t + 1);
      asm volatile("s_waitcnt vmcnt(8)" ::: "memory");  // tile t landed; t+1 in flight
    } else {
      asm volatile("s_waitcnt vmcnt(0)" ::: "memory");
    }
    asm volatile("s_barrier" ::: "memory");             // slot sl visible to all waves

    const unsigned char* Ap = As[sl];
    const unsigned char* Bp = Bs[sl];
    #define LDF(base, rowb, h, s) \
      (*(const i32x4*)((base) + ((((h) * 4 + (s)) << 12) + kq + (rowb))))
    #define FRAG(dst, base, rowb, h) do {               \
      i32x4 _lo = LDF(base, rowb, h, 0);                \
      i32x4 _hi = LDF(base, rowb, h, 1);                \
      dst[0]=_lo[0]; dst[1]=_lo[1]; dst[2]=_lo[2]; dst[3]=_lo[3]; \
      dst[4]=_hi[0]; dst[5]=_hi[1]; dst[6]=_hi[2]; dst[7]=_hi[3]; \
    } while (0)
    #define MFMA8(a, b, m, n) \
      acc[m][n] = __builtin_amdgcn_mfma_scale_f32_32x32x64_f8f6f4( \
          a, b, acc[m][n], 0, 0, 0, 127, 0, 127)

    #pragma unroll
    for (int h = 0; h < 2; ++h) {
      i32x8 b0, b1, a0, a1;
      FRAG(b0, Bp, brow[0], h); FRAG(b1, Bp, brow[1], h);
      FRAG(a0, Ap, arow[0], h); FRAG(a1, Ap, arow[1], h);
      __builtin_amdgcn_s_setprio(1);
      MFMA8(a0, b0, 0, 0); MFMA8(a0, b1, 0, 1);
      MFMA8(a1, b0, 1, 0); MFMA8(a1, b1, 1, 1);
      __builtin_amdgcn_s_setprio(0);
      FRAG(a0, Ap, arow[2], h); FRAG(a1, Ap, arow[3], h);
      __builtin_amdgcn_s_setprio(1);
      MFMA8(a0, b0, 2, 0); MFMA8(a0, b1, 2, 1);
      MFMA8(a1, b0, 3, 0); MFMA8(a1, b1, 3, 1);
      __builtin_amdgcn_s_setprio(0);
    }
    #undef LDF
    #undef FRAG
    #undef MFMA8
    asm volatile("s_barrier" ::: "memory");             // all reads of slot sl done
  }
  #undef STAGE

  // epilogue: 32x32 C/D layout (m74/m101): col=lane&31,
  // row = (reg&3) + 8*(reg>>2) + 4*(lane>>5)
  #pragma unroll
  for (int m = 0; m < 4; ++m) {
    const long rowb = Arow0 + wrow * 128 + m * 32;
    #pragma unroll
    for (int g4 = 0; g4 < 4; ++g4) {
      #pragma unroll
      for (int r4 = 0; r4 < 4; ++r4) {
        const long row = rowb + r4 + 8 * g4 + 4 * lk;
        float* cp = C + row * (long)ldc + Brow0 + wcol * 64 + l31;
        cp[0]  = acc[m][0][g4 * 4 + r4];
        cp[32] = acc[m][1][g4 * 4 + r4];
      }
    }
  }
}

// ---------------------------------------------------------------------------
// 5) 128x128 GEMM (m97 structure) for PV; blockIdx.z = split-K chunk.
//    C is bf16 partials: C[m][n] (+)= sum_k A[m][k+z*zk]*B[n][k+z*zk].
__global__ __launch_bounds__(256) void gemm_pv_k(
    const unsigned short* __restrict__ A, const unsigned short* __restrict__ B,
    unsigned short* __restrict__ C, int K, int lda, int ldb, int ldc,
    long zk, long zc, int accumulate)
{
  A += (long)blockIdx.z * zk;
  B += (long)blockIdx.z * zk;
  C += (long)blockIdx.z * zc;
  __shared__ __align__(16) unsigned short As[128 * 32];
  __shared__ __align__(16) unsigned short Bs[128 * 32];
  const int tid = threadIdx.x;
  const int lane = tid & 63;
  const int wave = tid >> 6;
  const int wm = (wave >> 1) * 64;
  const int wn = (wave & 1) * 64;
  const long Arow0 = (long)blockIdx.x * 128;
  const long Brow0 = (long)blockIdx.y * 128;

  f32x4 acc[4][4] = {};
  const int r  = lane & 15;
  const int kb = (lane >> 4) * 8;

  for (int k0 = 0; k0 < K; k0 += 32) {
    #pragma unroll
    for (int pass = 0; pass < 2; ++pass) {
      const int chunk = pass * 4 + wave;
      const int m  = chunk * 16 + (lane >> 2);
      const int ke = (lane & 3) * 8;
      gload_lds16(A + (Arow0 + m) * (long)lda + k0 + ke, &As[chunk * 512 + lane * 8]);
      gload_lds16(B + (Brow0 + m) * (long)ldb + k0 + ke, &Bs[chunk * 512 + lane * 8]);
    }
    __syncthreads();

    bf16x8 af[4], bfr[4];
    #pragma unroll
    for (int f = 0; f < 4; ++f) {
      af[f]  = *(const bf16x8*)&As[(wm + f * 16 + r) * 32 + kb];
      bfr[f] = *(const bf16x8*)&Bs[(wn + f * 16 + r) * 32 + kb];
    }
    #pragma unroll
    for (int i = 0; i < 4; ++i)
      #pragma unroll
      for (int j = 0; j < 4; ++j)
        acc[i][j] = __builtin_amdgcn_mfma_f32_16x16x32_bf16(af[i], bfr[j], acc[i][j], 0, 0, 0);
    __syncthreads();
  }

  const int rb = (lane >> 4) * 4;
  const int cn = lane & 15;
  #pragma unroll
  for (int i = 0; i < 4; ++i) {
    #pragma unroll
    for (int ii = 0; ii < 4; ++ii) {
      long m = Arow0 + wm + i * 16 + rb + ii;
      unsigned short* cp = C + m * (long)ldc + Brow0 + wn + cn;
      #pragma unroll
      for (int j = 0; j < 4; ++j) {
        float v = acc[i][j][ii];
        if (accumulate) v += bf2f(cp[j * 16]);
        cp[j * 16] = f2bf(v);
      }
    }
  }
}

// ---------------------------------------------------------------------------
// 6) row softmax, in-place fp32 -> bf16 (row = 3840 fp32; PV lda = 7680)
__global__ __launch_bounds__(256) void softmax_rows_k(float* __restrict__ logits)
{
  const int q = blockIdx.x;
  float* row = logits + (size_t)q * 3840;
  unsigned short* orow = (unsigned short*)row;
  const int tid = threadIdx.x;
  float v[15];
  float mx = -1e30f;
  #pragma unroll
  for (int j = 0; j < 15; ++j) {
    int s = tid + j * 256;
    float x = (s < 3600) ? row[s] : -1e30f;
    v[j] = x;
    mx = fmaxf(mx, x);
  }
  #pragma unroll
  for (int o = 32; o > 0; o >>= 1) mx = fmaxf(mx, __shfl_xor(mx, o));
  __shared__ float wmax[4], wsum[4];
  if ((tid & 63) == 0) wmax[tid >> 6] = mx;
  __syncthreads();
  mx = fmaxf(fmaxf(wmax[0], wmax[1]), fmaxf(wmax[2], wmax[3]));
  float sum = 0.f;
  #pragma unroll
  for (int j = 0; j < 15; ++j) {
    int s = tid + j * 256;
    float e = (s < 3600) ? __expf(v[j] - mx) : 0.f;
    v[j] = e;
    sum += e;
  }
  #pragma unroll
  for (int o = 32; o > 0; o >>= 1) sum += __shfl_xor(sum, o);
  if ((tid & 63) == 0) wsum[tid >> 6] = sum;
  __syncthreads();
  sum = wsum[0] + wsum[1] + wsum[2] + wsum[3];
  const float inv = 1.0f / sum;
  #pragma unroll
  for (int j = 0; j < 15; ++j) {
    int s = tid + j * 256;
    orow[s] = (s < 3600) ? f2bf(v[j] * inv) : (unsigned short)0;
  }
}

// ---------------------------------------------------------------------------
// 7) out[c][p] = 0.5*f_q[c][p] + 0.25*sum_z P[z][p][c]   (bf16 partials)
__global__ __launch_bounds__(256) void final_blend_k(
    const unsigned short* __restrict__ P, const float* __restrict__ fq,
    float* __restrict__ out)
{
  __shared__ float t[32][33];
  const int tx = threadIdx.x, ty = threadIdx.y;
  const int p0 = blockIdx.x * 32, c0 = blockIdx.y * 32;
  const long ZC = 3840L * 512;
  #pragma unroll
  for (int i = 0; i < 4; ++i) {
    int p = p0 + ty + i * 8, c = c0 + tx;
    float s = 0.f;
    if (p < 3600) {
      size_t o = (size_t)p * 512 + c;
      #pragma unroll
      for (int z = 0; z < 6; ++z) s += bf2f(P[o + (size_t)z * ZC]);
    }
    t[ty + i * 8][tx] = s;
  }
  __syncthreads();
  #pragma unroll
  for (int i = 0; i < 4; ++i) {
    int c = c0 + ty + i * 8, p = p0 + tx;
    if (p < 3600) {
      size_t o = (size_t)c * 3600 + p;
      out[o] = 0.5f * fq[o] + 0.25f * t[tx][ty + i * 8];
    }
  }
}

// ---------------------------------------------------------------------------
extern "C" void kernel_launch(void* const* d_in, const int* in_sizes, int n_in,
                              void* d_out, int out_size, void* d_ws, size_t ws_size,
                              hipStream_t stream) {
  const float* fq3 = (const float*)d_in[0];
  const float* fq4 = (const float*)d_in[1];
  const float* fs3 = (const float*)d_in[2];
  const float* fs4 = (const float*)d_in[3];
  const float* f_q = (const float*)d_in[4];
  const float* f_s = (const float*)d_in[5];
  const float* wch = (const float*)d_in[6];
  float* out = (float*)d_out;

  const size_t HW = 3600, MP = 3840, KC = 3072, CH = 512;

  // workspace (~110 MB); QT8/ST8 are K-group-major: chunk(g,p) at (g*MP+p)*16
  unsigned char* QT8 = (unsigned char*)d_ws;         // (KC/16, MP, 16B) fp8 query
  unsigned char* ST8 = QT8 + MP * KC;                // (KC/16, MP, 16B) fp8 support
  unsigned short* V  = (unsigned short*)(ST8 + MP * KC);  // (CH, MP) bf16
  float* logits = (float*)(V + CH * MP);             // (MP, MP) fp32; softmax -> bf16 in place
  unsigned short* Pb = (unsigned short*)(logits + MP * MP);  // 6 x (MP, CH) bf16 partials
  float* invn = (float*)(Pb + 6 * MP * CH);          // 6 x 3600
  float* part = logits;                              // norm scratch (consumed pre-GEMM)

  // zero QT8+ST8 entirely once (pads p>=3600 are interleaved per group;
  // tpose2 never writes them, and ST8's data region is fully rewritten per batch)
  hipMemsetAsync(QT8, 0, 2 * MP * KC, stream);
  hipMemsetAsync(V, 0, CH * MP * 2, stream);

  Src6 S;
  S.p[0] = fq4; S.p[1] = fs4; S.p[2] = fs4 + 2048 * HW;
  S.p[3] = fq3; S.p[4] = fs3; S.p[5] = fs3 + 1024 * HW;
  colnorm_part6_k<<<dim3(57, 16, 6), 256, 0, stream>>>(S, part);
  colnorm_fin6_k<<<dim3(15, 6), 256, 0, stream>>>(part, invn);

  dim3 tb(32, 8);
  tpose2_f8_k<<<dim3(113, 96), tb, 0, stream>>>(fq4, fq3, invn + 0 * HW, invn + 3 * HW,
                                                wch, 1, QT8);

  for (int b = 0; b < 2; ++b) {
    castv_k<<<7200, 256, 0, stream>>>(f_s + (size_t)b * CH * HW, V);
    tpose2_f8_k<<<dim3(113, 96), tb, 0, stream>>>(
        fs4 + (size_t)b * 2048 * HW, fs3 + (size_t)b * 1024 * HW,
        invn + (1 + b) * HW, invn + (4 + b) * HW, wch, 0, ST8);

    // logits[q][s] = sum_k QT8[q][k]*ST8[s][k] (MX-fp8, unit scales)
    gemm256_f8<<<225, 512, 0, stream>>>(QT8, ST8, logits, 3072, 3840, 3840, 15);

    softmax_rows_k<<<3600, 256, 0, stream>>>(logits);

    // PV split-K=6, bf16 partials
    gemm_pv_k<<<dim3(30, 4, 6), 256, 0, stream>>>(
        (const unsigned short*)logits, V, Pb, 640, 7680, 3840, 512,
        640L, 3840L * 512, b);
  }

  final_blend_k<<<dim3(113, 16), tb, 0, stream>>>(Pb, f_q, out);
}

// Round 10
// 321.224 us; speedup vs baseline: 1.3828x; 1.0357x over previous
//
#include <hip/hip_runtime.h>
#include <cstdint>

#define TEMP_C 20.0f

typedef float f32x4 __attribute__((ext_vector_type(4)));
typedef float f32x16 __attribute__((ext_vector_type(16)));
typedef int i32x4 __attribute__((ext_vector_type(4)));
typedef int i32x8 __attribute__((ext_vector_type(8)));

// fp32 -> bf16 round-to-nearest-even
__device__ __forceinline__ unsigned short f2bf(float f) {
  union { float f; unsigned int u; } v; v.f = f;
  unsigned int r = v.u + 0x7FFFu + ((v.u >> 16) & 1u);
  return (unsigned short)(r >> 16);
}
__device__ __forceinline__ float bf2f(unsigned short b) {
  union { unsigned int u; float f; } v; v.u = ((unsigned int)b) << 16;
  return v.f;
}

// fp32 -> OCP e4m3fn, RTNE, clamp to +-448
__device__ __forceinline__ unsigned char f2e4m3(float f) {
  unsigned u = __float_as_uint(f);
  unsigned s = (u >> 24) & 0x80u;
  float a = fminf(fabsf(f), 448.0f);
  if (a < 0.015625f) {
    int d = (int)rintf(a * 512.0f);
    return (unsigned char)(s | (unsigned)d);
  }
  unsigned au = __float_as_uint(a);
  unsigned r = au + 0xFFFFFu + ((au >> 20) & 1u);
  int Ep = (int)(r >> 23) - 127;
  if (Ep > 8) return (unsigned char)(s | 0x7E);
  unsigned m = (r >> 20) & 7u;
  return (unsigned char)(s | ((unsigned)(Ep + 7) << 3) | m);
}

// async global->LDS, 16B per lane (dest = wave-uniform base + lane*16)
__device__ __forceinline__ void gload_lds16(const void* g, void* l) {
  __builtin_amdgcn_global_load_lds(
      (__attribute__((address_space(1))) void*)(g),
      (__attribute__((address_space(3))) void*)(l), 16, 0, 0);
}

// ---------------------------------------------------------------------------
// 1a) partial sum-of-squares, all 6 feature slices in one launch.
struct Src6 { const float* p[6]; };

__global__ __launch_bounds__(256) void colnorm_part6_k(
    Src6 S, float* __restrict__ part)
{
  const int sl = blockIdx.z;
  const float* __restrict__ X = S.p[sl];
  const int C = (sl < 3) ? 2048 : 1024;
  const int cpc = C >> 4;
  __shared__ float red[4][64];
  const int pix = threadIdx.x & 63;
  const int sub = threadIdx.x >> 6;
  const int p = blockIdx.x * 64 + pix;
  const int c0 = blockIdx.y * cpc;
  float s = 0.f;
  if (p < 3600) {
    for (int c = c0 + sub; c < c0 + cpc; c += 4) {
      float v = X[(size_t)c * 3600 + p];
      s += v * v;
    }
  }
  red[sub][pix] = s;
  __syncthreads();
  if (sub == 0 && p < 3600) {
    part[(size_t)(sl * 16 + blockIdx.y) * 3600 + p] =
        red[0][pix] + red[1][pix] + red[2][pix] + red[3][pix];
  }
}

// 1b) finish all 6 slices
__global__ __launch_bounds__(256) void colnorm_fin6_k(
    const float* __restrict__ part, float* __restrict__ invn)
{
  const int z = blockIdx.y;
  const int p = blockIdx.x * 256 + threadIdx.x;
  if (p >= 3600) return;
  float s = 0.f;
  #pragma unroll
  for (int j = 0; j < 16; ++j) s += part[(size_t)(z * 16 + j) * 3600 + p];
  invn[(size_t)z * 3600 + p] = 1.0f / fmaxf(sqrtf(s), 1e-12f);
}

// ---------------------------------------------------------------------------
// 2) fused transpose+scale+FP8 cast, K-GROUP-MAJOR: T[(g*3840+p)*16 + (col&15)]
//    query side: mult = TEMP*w/4 ; support side: mult = 4  (product = TEMP*w)
__global__ __launch_bounds__(256) void tpose2_f8_k(
    const float* __restrict__ X4, const float* __restrict__ X3,
    const float* __restrict__ i4, const float* __restrict__ i3,
    const float* __restrict__ wch, int usew, unsigned char* __restrict__ T)
{
  __shared__ float tile[32][33];
  const int tx = threadIdx.x, ty = threadIdx.y;
  const int y = blockIdx.y;
  const float* X; const float* inv; int c0, cdst; float mult;
  if (y < 64) { X = X4; inv = i4; c0 = y * 32;        cdst = c0;        mult = usew ? TEMP_C * wch[0] * 0.25f : 4.0f; }
  else        { X = X3; inv = i3; c0 = (y - 64) * 32; cdst = 2048 + c0; mult = usew ? TEMP_C * wch[1] * 0.25f : 4.0f; }
  const int p0 = blockIdx.x * 32;
  #pragma unroll
  for (int i = 0; i < 4; ++i) {
    int c = c0 + ty + i * 8, p = p0 + tx;
    tile[ty + i * 8][tx] = (p < 3600) ? X[(size_t)c * 3600 + p] : 0.f;
  }
  __syncthreads();
  const int col = cdst + tx;
  const size_t gbase = (size_t)(col >> 4) * 3840 * 16 + (col & 15);
  #pragma unroll
  for (int i = 0; i < 4; ++i) {
    int p = p0 + ty + i * 8;
    if (p < 3600) {
      float sc = inv[p] * mult;
      T[gbase + (size_t)p * 16] = f2e4m3(tile[tx][ty + i * 8] * sc);
    }
  }
}

// ---------------------------------------------------------------------------
// 3) V cast to fp8, K-group-major over s: V8[((s>>4)*512 + c)*16 + (s&15)]
__global__ void castv_f8_k(const float* __restrict__ X, unsigned char* __restrict__ V8)
{
  int i = blockIdx.x * 256 + threadIdx.x;
  if (i >= 512 * 3600) return;
  int c = i / 3600, s = i - c * 3600;
  V8[((size_t)(s >> 4) * 512 + c) * 16 + (s & 15)] = f2e4m3(X[i]);
}

// ---------------------------------------------------------------------------
// 4) 256x256 MX-fp8 correlation GEMM (round 9 structure, verified 0-conflict).
//    Output now BF16 (halves write + softmax read traffic).
__global__ __launch_bounds__(512, 2) void gemm256_f8(
    const unsigned char* __restrict__ A, const unsigned char* __restrict__ B,
    unsigned short* __restrict__ C, int K, int MPr, int ldc, int nbn)
{
  __shared__ __align__(16) unsigned char As[2][256 * 128];
  __shared__ __align__(16) unsigned char Bs[2][256 * 128];

  const int tid  = threadIdx.x;
  const int lane = tid & 63;
  const int wave = tid >> 6;
  const int wrow = wave >> 2;
  const int wcol = wave & 3;

  // XCD-aware bijective block remap (m204)
  const int nwg = gridDim.x;
  const int q8 = nwg >> 3, r8 = nwg & 7;
  const int xcd = blockIdx.x & 7, bidx = blockIdx.x >> 3;
  const int wg = (xcd < r8 ? xcd * (q8 + 1) : r8 * (q8 + 1) + (xcd - r8) * q8) + bidx;
  const long Arow0 = (long)(wg / nbn) * 256;
  const long Brow0 = (long)(wg % nbn) * 256;

  const unsigned char* sA[4];
  const unsigned char* sB[4];
  #pragma unroll
  for (int q = 0; q < 4; ++q) {
    const int c = q * 512 + tid;
    sA[q] = A + ((long)(c >> 8) * MPr + Arow0 + (c & 255)) * 16;
    sB[q] = B + ((long)(c >> 8) * MPr + Brow0 + (c & 255)) * 16;
  }
  const long kstride = (long)MPr * 16 * 8;

  #define STAGE(tt) do {                                        \
    const long _ko = (long)(tt) * kstride; const int _sl = (tt) & 1; \
    _Pragma("unroll")                                           \
    for (int q = 0; q < 4; ++q)                                 \
      gload_lds16(sA[q] + _ko, &As[_sl][(q * 512 + tid) * 16]); \
    _Pragma("unroll")                                           \
    for (int q = 0; q < 4; ++q)                                 \
      gload_lds16(sB[q] + _ko, &Bs[_sl][(q * 512 + tid) * 16]); \
  } while (0)

  const int l31 = lane & 31, lk = lane >> 5;
  int arow[4], brow[2];
  #pragma unroll
  for (int m = 0; m < 4; ++m) arow[m] = (wrow * 128 + m * 32 + l31) * 16;
  #pragma unroll
  for (int n = 0; n < 2; ++n) brow[n] = (wcol * 64 + n * 32 + l31) * 16;
  const int kq = (lk * 2) << 12;

  f32x16 acc[4][2] = {};
  const int NT = K >> 7;

  STAGE(0);

  for (int t = 0; t < NT; ++t) {
    const int sl = t & 1;
    if (t + 1 < NT) {
      STAGE(t + 1);
      asm volatile("s_waitcnt vmcnt(8)" ::: "memory");
    } else {
      asm volatile("s_waitcnt vmcnt(0)" ::: "memory");
    }
    asm volatile("s_barrier" ::: "memory");

    const unsigned char* Ap = As[sl];
    const unsigned char* Bp = Bs[sl];
    #define LDF(base, rowb, h, s) \
      (*(const i32x4*)((base) + ((((h) * 4 + (s)) << 12) + kq + (rowb))))
    #define FRAG(dst, base, rowb, h) do {               \
      i32x4 _lo = LDF(base, rowb, h, 0);                \
      i32x4 _hi = LDF(base, rowb, h, 1);                \
      dst[0]=_lo[0]; dst[1]=_lo[1]; dst[2]=_lo[2]; dst[3]=_lo[3]; \
      dst[4]=_hi[0]; dst[5]=_hi[1]; dst[6]=_hi[2]; dst[7]=_hi[3]; \
    } while (0)
    #define MFMA8(a, b, m, n) \
      acc[m][n] = __builtin_amdgcn_mfma_scale_f32_32x32x64_f8f6f4( \
          a, b, acc[m][n], 0, 0, 0, 127, 0, 127)

    #pragma unroll
    for (int h = 0; h < 2; ++h) {
      i32x8 b0, b1, a0, a1;
      FRAG(b0, Bp, brow[0], h); FRAG(b1, Bp, brow[1], h);
      FRAG(a0, Ap, arow[0], h); FRAG(a1, Ap, arow[1], h);
      __builtin_amdgcn_s_setprio(1);
      MFMA8(a0, b0, 0, 0); MFMA8(a0, b1, 0, 1);
      MFMA8(a1, b0, 1, 0); MFMA8(a1, b1, 1, 1);
      __builtin_amdgcn_s_setprio(0);
      FRAG(a0, Ap, arow[2], h); FRAG(a1, Ap, arow[3], h);
      __builtin_amdgcn_s_setprio(1);
      MFMA8(a0, b0, 2, 0); MFMA8(a0, b1, 2, 1);
      MFMA8(a1, b0, 3, 0); MFMA8(a1, b1, 3, 1);
      __builtin_amdgcn_s_setprio(0);
    }
    #undef LDF
    #undef FRAG
    #undef MFMA8
    asm volatile("s_barrier" ::: "memory");
  }
  #undef STAGE

  // epilogue (bf16): col=lane&31, row = (reg&3) + 8*(reg>>2) + 4*(lane>>5)
  #pragma unroll
  for (int m = 0; m < 4; ++m) {
    const long rowb = Arow0 + wrow * 128 + m * 32;
    #pragma unroll
    for (int g4 = 0; g4 < 4; ++g4) {
      #pragma unroll
      for (int r4 = 0; r4 < 4; ++r4) {
        const long row = rowb + r4 + 8 * g4 + 4 * lk;
        unsigned short* cp = C + row * (long)ldc + Brow0 + wcol * 64 + l31;
        cp[0]  = f2bf(acc[m][0][g4 * 4 + r4]);
        cp[32] = f2bf(acc[m][1][g4 * 4 + r4]);
      }
    }
  }
}

// ---------------------------------------------------------------------------
// 5) PV MX-fp8 GEMM: P[z][q][c] (+)= sum_{s in chunk z} Att8[q][s]*V8[c][s].
//    Att8/V8 K-group-major (g = s>>4): Att8 chunk (g,q) at (g*3840+q)*16,
//    V8 chunk (g,c) at (g*512+c)*16. 128x128 tile, BK=128 (8 groups),
//    4 waves (2x2 of 64x64), 2 LDS slots = 64KB -> 2 blocks/CU.
//    grid (30,4,6): z = split-K chunk of 40 groups (640 s). Counted vmcnt(8).
//    Output bf16 partials (scaled by 448 from attn quantization).
__global__ __launch_bounds__(256, 2) void pv_f8_k(
    const unsigned char* __restrict__ Att, const unsigned char* __restrict__ V,
    unsigned short* __restrict__ P, int accumulate)
{
  __shared__ __align__(16) unsigned char As[2][128 * 128];
  __shared__ __align__(16) unsigned char Bs[2][128 * 128];

  const int tid  = threadIdx.x;
  const int lane = tid & 63;
  const int wave = tid >> 6;     // 0..3
  const int wrow = wave >> 1;    // 0..1 (q half)
  const int wcol = wave & 1;     // 0..1 (c half)
  const long Arow0 = (long)blockIdx.x * 128;   // q
  const long Brow0 = (long)blockIdx.y * 128;   // c
  const int z = blockIdx.z;
  P += (long)z * 3840 * 512;

  const unsigned char* sA[4];
  const unsigned char* sB[4];
  #pragma unroll
  for (int q = 0; q < 4; ++q) {
    const int c = q * 256 + tid;
    const int g = c >> 7, r = c & 127;
    sA[q] = Att + ((long)(z * 40 + g) * 3840 + Arow0 + r) * 16;
    sB[q] = V   + ((long)(z * 40 + g) * 512  + Brow0 + r) * 16;
  }
  const long ksA = 3840L * 16 * 8;   // 8 groups per K-tile
  const long ksB = 512L * 16 * 8;

  #define STAGE(tt) do { const int _sl = (tt) & 1;                          \
    _Pragma("unroll")                                                       \
    for (int q = 0; q < 4; ++q)                                             \
      gload_lds16(sA[q] + (long)(tt) * ksA, &As[_sl][(q * 256 + tid) * 16]);\
    _Pragma("unroll")                                                       \
    for (int q = 0; q < 4; ++q)                                             \
      gload_lds16(sB[q] + (long)(tt) * ksB, &Bs[_sl][(q * 256 + tid) * 16]);\
  } while (0)

  const int l31 = lane & 31, lk = lane >> 5;
  const int arow0 = (wrow * 64 + l31) * 16;   // +32*16 for m=1
  const int brow0 = (wcol * 64 + l31) * 16;

  f32x16 acc[2][2] = {};
  const int NT = 5;   // 640 / 128

  STAGE(0);

  for (int t = 0; t < NT; ++t) {
    const int sl = t & 1;
    if (t + 1 < NT) {
      STAGE(t + 1);
      asm volatile("s_waitcnt vmcnt(8)" ::: "memory");
    } else {
      asm volatile("s_waitcnt vmcnt(0)" ::: "memory");
    }
    asm volatile("s_barrier" ::: "memory");

    const unsigned char* Ap = As[sl];
    const unsigned char* Bp = Bs[sl];
    // group stride in LDS = 128*16 = 2048B
    #define LDF(base, rowb, h, s) \
      (*(const i32x4*)((base) + ((((h) * 4 + lk * 2 + (s)) << 11) + (rowb))))
    #define FRAG(dst, base, rowb, h) do {               \
      i32x4 _lo = LDF(base, rowb, h, 0);                \
      i32x4 _hi = LDF(base, rowb, h, 1);                \
      dst[0]=_lo[0]; dst[1]=_lo[1]; dst[2]=_lo[2]; dst[3]=_lo[3]; \
      dst[4]=_hi[0]; dst[5]=_hi[1]; dst[6]=_hi[2]; dst[7]=_hi[3]; \
    } while (0)
    #define MFMA8(a, b, m, n) \
      acc[m][n] = __builtin_amdgcn_mfma_scale_f32_32x32x64_f8f6f4( \
          a, b, acc[m][n], 0, 0, 0, 127, 0, 127)

    #pragma unroll
    for (int h = 0; h < 2; ++h) {
      i32x8 a0, a1, b0, b1;
      FRAG(a0, Ap, arow0, h); FRAG(a1, Ap, arow0 + 512, h);   // +32 rows
      FRAG(b0, Bp, brow0, h); FRAG(b1, Bp, brow0 + 512, h);
      __builtin_amdgcn_s_setprio(1);
      MFMA8(a0, b0, 0, 0); MFMA8(a0, b1, 0, 1);
      MFMA8(a1, b0, 1, 0); MFMA8(a1, b1, 1, 1);
      __builtin_amdgcn_s_setprio(0);
    }
    #undef LDF
    #undef FRAG
    #undef MFMA8
    asm volatile("s_barrier" ::: "memory");
  }
  #undef STAGE

  // epilogue: col=lane&31, row = (reg&3)+8*(reg>>2)+4*(lane>>5); bf16 RMW
  #pragma unroll
  for (int m = 0; m < 2; ++m) {
    const long rowb = Arow0 + wrow * 64 + m * 32;
    #pragma unroll
    for (int g4 = 0; g4 < 4; ++g4) {
      #pragma unroll
      for (int r4 = 0; r4 < 4; ++r4) {
        const long row = rowb + r4 + 8 * g4 + 4 * lk;
        unsigned short* cp = P + row * 512 + Brow0 + wcol * 64 + l31;
        float v0 = acc[m][0][g4 * 4 + r4];
        float v1 = acc[m][1][g4 * 4 + r4];
        if (accumulate) { v0 += bf2f(cp[0]); v1 += bf2f(cp[32]); }
        cp[0]  = f2bf(v0);
        cp[32] = f2bf(v1);
      }
    }
  }
}

// ---------------------------------------------------------------------------
// 6) row softmax: reads bf16 logits (ldr 3840), writes fp8 attn*448 into
//    K-group-major Att8 (pad s in [3600,3840) written 0 every call).
__global__ __launch_bounds__(256) void softmax_rows_k(
    const unsigned short* __restrict__ Lb, unsigned char* __restrict__ Att)
{
  const int q = blockIdx.x;
  const unsigned short* row = Lb + (size_t)q * 3840;
  const int tid = threadIdx.x;
  float v[15];
  float mx = -1e30f;
  #pragma unroll
  for (int j = 0; j < 15; ++j) {
    int s = tid + j * 256;
    float x = (s < 3600) ? bf2f(row[s]) : -1e30f;
    v[j] = x;
    mx = fmaxf(mx, x);
  }
  #pragma unroll
  for (int o = 32; o > 0; o >>= 1) mx = fmaxf(mx, __shfl_xor(mx, o));
  __shared__ float wmax[4], wsum[4];
  if ((tid & 63) == 0) wmax[tid >> 6] = mx;
  __syncthreads();
  mx = fmaxf(fmaxf(wmax[0], wmax[1]), fmaxf(wmax[2], wmax[3]));
  float sum = 0.f;
  #pragma unroll
  for (int j = 0; j < 15; ++j) {
    int s = tid + j * 256;
    float e = (s < 3600) ? __expf(v[j] - mx) : 0.f;
    v[j] = e;
    sum += e;
  }
  #pragma unroll
  for (int o = 32; o > 0; o >>= 1) sum += __shfl_xor(sum, o);
  if ((tid & 63) == 0) wsum[tid >> 6] = sum;
  __syncthreads();
  sum = wsum[0] + wsum[1] + wsum[2] + wsum[3];
  const float inv448 = 448.0f / sum;
  #pragma unroll
  for (int j = 0; j < 15; ++j) {
    int s = tid + j * 256;
    unsigned char b = (s < 3600) ? f2e4m3(v[j] * inv448) : (unsigned char)0;
    Att[((size_t)(s >> 4) * 3840 + q) * 16 + (s & 15)] = b;
  }
}

// ---------------------------------------------------------------------------
// 7) out[c][p] = 0.5*f_q[c][p] + (0.25/448)*sum_z P[z][p][c]  (bf16 partials)
__global__ __launch_bounds__(256) void final_blend_k(
    const unsigned short* __restrict__ P, const float* __restrict__ fq,
    float* __restrict__ out)
{
  __shared__ float t[32][33];
  const int tx = threadIdx.x, ty = threadIdx.y;
  const int p0 = blockIdx.x * 32, c0 = blockIdx.y * 32;
  const long ZC = 3840L * 512;
  #pragma unroll
  for (int i = 0; i < 4; ++i) {
    int p = p0 + ty + i * 8, c = c0 + tx;
    float s = 0.f;
    if (p < 3600) {
      size_t o = (size_t)p * 512 + c;
      #pragma unroll
      for (int z = 0; z < 6; ++z) s += bf2f(P[o + (size_t)z * ZC]);
    }
    t[ty + i * 8][tx] = s;
  }
  __syncthreads();
  const float wts = 0.25f / 448.0f;
  #pragma unroll
  for (int i = 0; i < 4; ++i) {
    int c = c0 + ty + i * 8, p = p0 + tx;
    if (p < 3600) {
      size_t o = (size_t)c * 3600 + p;
      out[o] = 0.5f * fq[o] + wts * t[tx][ty + i * 8];
    }
  }
}

// ---------------------------------------------------------------------------
extern "C" void kernel_launch(void* const* d_in, const int* in_sizes, int n_in,
                              void* d_out, int out_size, void* d_ws, size_t ws_size,
                              hipStream_t stream) {
  const float* fq3 = (const float*)d_in[0];
  const float* fq4 = (const float*)d_in[1];
  const float* fs3 = (const float*)d_in[2];
  const float* fs4 = (const float*)d_in[3];
  const float* f_q = (const float*)d_in[4];
  const float* f_s = (const float*)d_in[5];
  const float* wch = (const float*)d_in[6];
  float* out = (float*)d_out;

  const size_t HW = 3600, MP = 3840, KC = 3072, CH = 512;

  // workspace (~94 MB); no pad memsets needed: pad rows/cols only affect
  // discarded outputs (q,s >= 3600), attn pad is written 0 each call,
  // and 0xAA poison is not an e4m3 NaN.
  unsigned char* QT8 = (unsigned char*)d_ws;          // (KC/16, MP, 16B) fp8 query
  unsigned char* ST8 = QT8 + MP * KC;                 // (KC/16, MP, 16B) fp8 support
  unsigned char* V8  = ST8 + MP * KC;                 // (MP/16, CH, 16B) fp8 V
  unsigned short* Lb = (unsigned short*)(V8 + (MP / 16) * CH * 16);  // (MP,MP) bf16 logits
  unsigned char* Att8 = (unsigned char*)(Lb + MP * MP);  // (MP/16, MP, 16B) fp8 attn*448
  unsigned short* Pb = (unsigned short*)(Att8 + (MP / 16) * MP * 16); // 6 x (MP,CH) bf16
  float* invn = (float*)(Pb + 6 * MP * CH);           // 6 x 3600
  float* part = (float*)Lb;                           // norm scratch (consumed pre-GEMM)

  Src6 S;
  S.p[0] = fq4; S.p[1] = fs4; S.p[2] = fs4 + 2048 * HW;
  S.p[3] = fq3; S.p[4] = fs3; S.p[5] = fs3 + 1024 * HW;
  colnorm_part6_k<<<dim3(57, 16, 6), 256, 0, stream>>>(S, part);
  colnorm_fin6_k<<<dim3(15, 6), 256, 0, stream>>>(part, invn);

  dim3 tb(32, 8);
  tpose2_f8_k<<<dim3(113, 96), tb, 0, stream>>>(fq4, fq3, invn + 0 * HW, invn + 3 * HW,
                                                wch, 1, QT8);

  for (int b = 0; b < 2; ++b) {
    castv_f8_k<<<7200, 256, 0, stream>>>(f_s + (size_t)b * CH * HW, V8);
    tpose2_f8_k<<<dim3(113, 96), tb, 0, stream>>>(
        fs4 + (size_t)b * 2048 * HW, fs3 + (size_t)b * 1024 * HW,
        invn + (1 + b) * HW, invn + (4 + b) * HW, wch, 0, ST8);

    // logits (bf16) = QT8 . ST8^T (MX-fp8, unit scales)
    gemm256_f8<<<225, 512, 0, stream>>>(QT8, ST8, Lb, 3072, 3840, 3840, 15);

    softmax_rows_k<<<3600, 256, 0, stream>>>(Lb, Att8);

    // PV split-K=6, fp8 x fp8 -> bf16 partials (scale 448 folded in attn)
    pv_f8_k<<<dim3(30, 4, 6), 256, 0, stream>>>(Att8, V8, Pb, b);
  }

  final_blend_k<<<dim3(113, 16), tb, 0, stream>>>(Pb, f_q, out);
}

// Round 11
// 315.951 us; speedup vs baseline: 1.4059x; 1.0167x over previous
//
#include <hip/hip_runtime.h>
#include <cstdint>

#define TEMP_C 20.0f

typedef float f32x4 __attribute__((ext_vector_type(4)));
typedef float f32x16 __attribute__((ext_vector_type(16)));
typedef int i32x4 __attribute__((ext_vector_type(4)));
typedef int i32x8 __attribute__((ext_vector_type(8)));

// fp32 -> bf16 round-to-nearest-even
__device__ __forceinline__ unsigned short f2bf(float f) {
  union { float f; unsigned int u; } v; v.f = f;
  unsigned int r = v.u + 0x7FFFu + ((v.u >> 16) & 1u);
  return (unsigned short)(r >> 16);
}
__device__ __forceinline__ float bf2f(unsigned short b) {
  union { unsigned int u; float f; } v; v.u = ((unsigned int)b) << 16;
  return v.f;
}

// fp32 -> OCP e4m3fn, RTNE, clamp to +-448
__device__ __forceinline__ unsigned char f2e4m3(float f) {
  unsigned u = __float_as_uint(f);
  unsigned s = (u >> 24) & 0x80u;
  float a = fminf(fabsf(f), 448.0f);
  if (a < 0.015625f) {
    int d = (int)rintf(a * 512.0f);
    return (unsigned char)(s | (unsigned)d);
  }
  unsigned au = __float_as_uint(a);
  unsigned r = au + 0xFFFFFu + ((au >> 20) & 1u);
  int Ep = (int)(r >> 23) - 127;
  if (Ep > 8) return (unsigned char)(s | 0x7E);
  unsigned m = (r >> 20) & 7u;
  return (unsigned char)(s | ((unsigned)(Ep + 7) << 3) | m);
}

// async global->LDS, 16B per lane (dest = wave-uniform base + lane*16)
__device__ __forceinline__ void gload_lds16(const void* g, void* l) {
  __builtin_amdgcn_global_load_lds(
      (__attribute__((address_space(1))) void*)(g),
      (__attribute__((address_space(3))) void*)(l), 16, 0, 0);
}

// ---------------------------------------------------------------------------
// 1a) partial sum-of-squares, all 6 feature slices in one launch.
struct Src6 { const float* p[6]; };

__global__ __launch_bounds__(256) void colnorm_part6_k(
    Src6 S, float* __restrict__ part)
{
  const int sl = blockIdx.z;
  const float* __restrict__ X = S.p[sl];
  const int C = (sl < 3) ? 2048 : 1024;
  const int cpc = C >> 4;
  __shared__ float red[4][64];
  const int pix = threadIdx.x & 63;
  const int sub = threadIdx.x >> 6;
  const int p = blockIdx.x * 64 + pix;
  const int c0 = blockIdx.y * cpc;
  float s = 0.f;
  if (p < 3600) {
    for (int c = c0 + sub; c < c0 + cpc; c += 4) {
      float v = X[(size_t)c * 3600 + p];
      s += v * v;
    }
  }
  red[sub][pix] = s;
  __syncthreads();
  if (sub == 0 && p < 3600) {
    part[(size_t)(sl * 16 + blockIdx.y) * 3600 + p] =
        red[0][pix] + red[1][pix] + red[2][pix] + red[3][pix];
  }
}

// 1b) finish all 6 slices
__global__ __launch_bounds__(256) void colnorm_fin6_k(
    const float* __restrict__ part, float* __restrict__ invn)
{
  const int z = blockIdx.y;
  const int p = blockIdx.x * 256 + threadIdx.x;
  if (p >= 3600) return;
  float s = 0.f;
  #pragma unroll
  for (int j = 0; j < 16; ++j) s += part[(size_t)(z * 16 + j) * 3600 + p];
  invn[(size_t)z * 3600 + p] = 1.0f / fmaxf(sqrtf(s), 1e-12f);
}

// ---------------------------------------------------------------------------
// 2) fused transpose+scale+FP8 cast, K-GROUP-MAJOR: T[(g*3840+p)*16 + (col&15)]
//    query side: mult = TEMP*w/4 ; support side: mult = 4  (product = TEMP*w)
__global__ __launch_bounds__(256) void tpose2_f8_k(
    const float* __restrict__ X4, const float* __restrict__ X3,
    const float* __restrict__ i4, const float* __restrict__ i3,
    const float* __restrict__ wch, int usew, unsigned char* __restrict__ T)
{
  __shared__ float tile[32][33];
  const int tx = threadIdx.x, ty = threadIdx.y;
  const int y = blockIdx.y;
  const float* X; const float* inv; int c0, cdst; float mult;
  if (y < 64) { X = X4; inv = i4; c0 = y * 32;        cdst = c0;        mult = usew ? TEMP_C * wch[0] * 0.25f : 4.0f; }
  else        { X = X3; inv = i3; c0 = (y - 64) * 32; cdst = 2048 + c0; mult = usew ? TEMP_C * wch[1] * 0.25f : 4.0f; }
  const int p0 = blockIdx.x * 32;
  #pragma unroll
  for (int i = 0; i < 4; ++i) {
    int c = c0 + ty + i * 8, p = p0 + tx;
    tile[ty + i * 8][tx] = (p < 3600) ? X[(size_t)c * 3600 + p] : 0.f;
  }
  __syncthreads();
  const int col = cdst + tx;
  const size_t gbase = (size_t)(col >> 4) * 3840 * 16 + (col & 15);
  #pragma unroll
  for (int i = 0; i < 4; ++i) {
    int p = p0 + ty + i * 8;
    if (p < 3600) {
      float sc = inv[p] * mult;
      T[gbase + (size_t)p * 16] = f2e4m3(tile[tx][ty + i * 8] * sc);
    }
  }
}

// ---------------------------------------------------------------------------
// 3) V cast to fp8, K-group-major over s: V8[((s>>4)*512 + c)*16 + (s&15)]
__global__ void castv_f8_k(const float* __restrict__ X, unsigned char* __restrict__ V8)
{
  int i = blockIdx.x * 256 + threadIdx.x;
  if (i >= 512 * 3600) return;
  int c = i / 3600, s = i - c * 3600;
  V8[((size_t)(s >> 4) * 512 + c) * 16 + (s & 15)] = f2e4m3(X[i]);
}

// ---------------------------------------------------------------------------
// 4) 128x128 MX-fp8 correlation GEMM, 4 waves (2Mx2N), BK=64, 2 LDS slots
//    = 32KB -> 4 blocks/CU (launch_bounds(256,4); acc=64 regs fits 128 cap).
//    900 blocks => ~3.5 resident blocks/CU: cross-block overlap of LDS reads
//    and MFMA replaces the failed intra-block scheduling attempts (r5-7).
//    Same proven pieces as r9/r10: 16B-group-major operands (coalesced
//    staging, 2-way-free banks), counted vmcnt(4) depth-1 prefetch,
//    mfma_scale 32x32x64, verified C/D epilogue. Output bf16.
__global__ __launch_bounds__(256, 4) void gemm128_f8(
    const unsigned char* __restrict__ A, const unsigned char* __restrict__ B,
    unsigned short* __restrict__ C, int K, int MPr, int ldc, int nbn)
{
  __shared__ __align__(16) unsigned char As[2][8192];   // [4 g][128 rows][16B]
  __shared__ __align__(16) unsigned char Bs[2][8192];

  const int tid  = threadIdx.x;
  const int lane = tid & 63;
  const int wave = tid >> 6;     // 0..3
  const int wrow = wave >> 1;    // 0..1 (M half)
  const int wcol = wave & 1;     // 0..1 (N half)

  // XCD-aware bijective block remap (m204)
  const int nwg = gridDim.x;
  const int q8 = nwg >> 3, r8 = nwg & 7;
  const int xcd = blockIdx.x & 7, bidx = blockIdx.x >> 3;
  const int wg = (xcd < r8 ? xcd * (q8 + 1) : r8 * (q8 + 1) + (xcd - r8) * q8) + bidx;
  const long Arow0 = (long)(wg / nbn) * 128;
  const long Brow0 = (long)(wg % nbn) * 128;

  // staging: 512 chunks of 16B per operand per slot; thread owns c = tid, 256+tid.
  // chunk c = (g = c>>7, r = c&127); LDS dest linear c*16 (gload_lds req).
  const unsigned char* sA[2];
  const unsigned char* sB[2];
  #pragma unroll
  for (int q = 0; q < 2; ++q) {
    const int c = q * 256 + tid;
    const int g = c >> 7, r = c & 127;
    sA[q] = A + ((long)g * MPr + Arow0 + r) * 16;
    sB[q] = B + ((long)g * MPr + Brow0 + r) * 16;
  }
  const long kstride = (long)MPr * 16 * 4;   // 4 groups per K-tile (BK=64)

  #define STAGE(tt) do { const int _sl = (tt) & 1; const long _ko = (long)(tt) * kstride; \
    gload_lds16(sA[0] + _ko, &As[_sl][tid * 16]);              \
    gload_lds16(sA[1] + _ko, &As[_sl][(256 + tid) * 16]);      \
    gload_lds16(sB[0] + _ko, &Bs[_sl][tid * 16]);              \
    gload_lds16(sB[1] + _ko, &Bs[_sl][(256 + tid) * 16]);      \
  } while (0)

  const int l31 = lane & 31, lk = lane >> 5;
  const int arow0 = (wrow * 64 + l31) * 16;   // m-tile 0; m=1 at +32 rows (=+512B)
  const int brow0 = (wcol * 64 + l31) * 16;

  f32x16 acc[2][2] = {};
  const int NT = K >> 6;   // 48 K-tiles

  STAGE(0);

  for (int t = 0; t < NT; ++t) {
    const int sl = t & 1;
    if (t + 1 < NT) {
      STAGE(t + 1);
      asm volatile("s_waitcnt vmcnt(4)" ::: "memory");  // tile t landed; t+1 in flight
    } else {
      asm volatile("s_waitcnt vmcnt(0)" ::: "memory");
    }
    asm volatile("s_barrier" ::: "memory");             // slot sl visible to all waves

    const unsigned char* Ap = As[sl];
    const unsigned char* Bp = Bs[sl];
    // group stride 2048B; lane's k-groups = lk*2 + {0,1}
    #define LDF(base, rowb, s) (*(const i32x4*)((base) + (((lk * 2 + (s)) << 11) + (rowb))))
    #define FRAG(dst, base, rowb) do {                  \
      i32x4 _lo = LDF(base, rowb, 0);                   \
      i32x4 _hi = LDF(base, rowb, 1);                   \
      dst[0]=_lo[0]; dst[1]=_lo[1]; dst[2]=_lo[2]; dst[3]=_lo[3]; \
      dst[4]=_hi[0]; dst[5]=_hi[1]; dst[6]=_hi[2]; dst[7]=_hi[3]; \
    } while (0)
    #define MFMA8(a, b, m, n) \
      acc[m][n] = __builtin_amdgcn_mfma_scale_f32_32x32x64_f8f6f4( \
          a, b, acc[m][n], 0, 0, 0, 127, 0, 127)

    i32x8 a0, a1, b0, b1;
    FRAG(a0, Ap, arow0); FRAG(a1, Ap, arow0 + 512);
    FRAG(b0, Bp, brow0); FRAG(b1, Bp, brow0 + 512);
    __builtin_amdgcn_s_setprio(1);
    MFMA8(a0, b0, 0, 0); MFMA8(a0, b1, 0, 1);
    MFMA8(a1, b0, 1, 0); MFMA8(a1, b1, 1, 1);
    __builtin_amdgcn_s_setprio(0);
    #undef LDF
    #undef FRAG
    #undef MFMA8
    asm volatile("s_barrier" ::: "memory");             // all reads of slot sl done
  }
  #undef STAGE

  // epilogue (bf16): col=lane&31, row = (reg&3) + 8*(reg>>2) + 4*(lane>>5)
  #pragma unroll
  for (int m = 0; m < 2; ++m) {
    const long rowb = Arow0 + wrow * 64 + m * 32;
    #pragma unroll
    for (int g4 = 0; g4 < 4; ++g4) {
      #pragma unroll
      for (int r4 = 0; r4 < 4; ++r4) {
        const long row = rowb + r4 + 8 * g4 + 4 * lk;
        unsigned short* cp = C + row * (long)ldc + Brow0 + wcol * 64 + l31;
        cp[0]  = f2bf(acc[m][0][g4 * 4 + r4]);
        cp[32] = f2bf(acc[m][1][g4 * 4 + r4]);
      }
    }
  }
}

// ---------------------------------------------------------------------------
// 5) PV MX-fp8 GEMM (round 10, verified): P[z][q][c] (+)= Att8[q][s]*V8[c][s].
__global__ __launch_bounds__(256, 2) void pv_f8_k(
    const unsigned char* __restrict__ Att, const unsigned char* __restrict__ V,
    unsigned short* __restrict__ P, int accumulate)
{
  __shared__ __align__(16) unsigned char As[2][128 * 128];
  __shared__ __align__(16) unsigned char Bs[2][128 * 128];

  const int tid  = threadIdx.x;
  const int lane = tid & 63;
  const int wave = tid >> 6;
  const int wrow = wave >> 1;
  const int wcol = wave & 1;
  const long Arow0 = (long)blockIdx.x * 128;   // q
  const long Brow0 = (long)blockIdx.y * 128;   // c
  const int z = blockIdx.z;
  P += (long)z * 3840 * 512;

  const unsigned char* sA[4];
  const unsigned char* sB[4];
  #pragma unroll
  for (int q = 0; q < 4; ++q) {
    const int c = q * 256 + tid;
    const int g = c >> 7, r = c & 127;
    sA[q] = Att + ((long)(z * 40 + g) * 3840 + Arow0 + r) * 16;
    sB[q] = V   + ((long)(z * 40 + g) * 512  + Brow0 + r) * 16;
  }
  const long ksA = 3840L * 16 * 8;
  const long ksB = 512L * 16 * 8;

  #define STAGE(tt) do { const int _sl = (tt) & 1;                          \
    _Pragma("unroll")                                                       \
    for (int q = 0; q < 4; ++q)                                             \
      gload_lds16(sA[q] + (long)(tt) * ksA, &As[_sl][(q * 256 + tid) * 16]);\
    _Pragma("unroll")                                                       \
    for (int q = 0; q < 4; ++q)                                             \
      gload_lds16(sB[q] + (long)(tt) * ksB, &Bs[_sl][(q * 256 + tid) * 16]);\
  } while (0)

  const int l31 = lane & 31, lk = lane >> 5;
  const int arow0 = (wrow * 64 + l31) * 16;
  const int brow0 = (wcol * 64 + l31) * 16;

  f32x16 acc[2][2] = {};
  const int NT = 5;

  STAGE(0);

  for (int t = 0; t < NT; ++t) {
    const int sl = t & 1;
    if (t + 1 < NT) {
      STAGE(t + 1);
      asm volatile("s_waitcnt vmcnt(8)" ::: "memory");
    } else {
      asm volatile("s_waitcnt vmcnt(0)" ::: "memory");
    }
    asm volatile("s_barrier" ::: "memory");

    const unsigned char* Ap = As[sl];
    const unsigned char* Bp = Bs[sl];
    #define LDF(base, rowb, h, s) \
      (*(const i32x4*)((base) + ((((h) * 4 + lk * 2 + (s)) << 11) + (rowb))))
    #define FRAG(dst, base, rowb, h) do {               \
      i32x4 _lo = LDF(base, rowb, h, 0);                \
      i32x4 _hi = LDF(base, rowb, h, 1);                \
      dst[0]=_lo[0]; dst[1]=_lo[1]; dst[2]=_lo[2]; dst[3]=_lo[3]; \
      dst[4]=_hi[0]; dst[5]=_hi[1]; dst[6]=_hi[2]; dst[7]=_hi[3]; \
    } while (0)
    #define MFMA8(a, b, m, n) \
      acc[m][n] = __builtin_amdgcn_mfma_scale_f32_32x32x64_f8f6f4( \
          a, b, acc[m][n], 0, 0, 0, 127, 0, 127)

    #pragma unroll
    for (int h = 0; h < 2; ++h) {
      i32x8 a0, a1, b0, b1;
      FRAG(a0, Ap, arow0, h); FRAG(a1, Ap, arow0 + 512, h);
      FRAG(b0, Bp, brow0, h); FRAG(b1, Bp, brow0 + 512, h);
      __builtin_amdgcn_s_setprio(1);
      MFMA8(a0, b0, 0, 0); MFMA8(a0, b1, 0, 1);
      MFMA8(a1, b0, 1, 0); MFMA8(a1, b1, 1, 1);
      __builtin_amdgcn_s_setprio(0);
    }
    #undef LDF
    #undef FRAG
    #undef MFMA8
    asm volatile("s_barrier" ::: "memory");
  }
  #undef STAGE

  #pragma unroll
  for (int m = 0; m < 2; ++m) {
    const long rowb = Arow0 + wrow * 64 + m * 32;
    #pragma unroll
    for (int g4 = 0; g4 < 4; ++g4) {
      #pragma unroll
      for (int r4 = 0; r4 < 4; ++r4) {
        const long row = rowb + r4 + 8 * g4 + 4 * lk;
        unsigned short* cp = P + row * 512 + Brow0 + wcol * 64 + l31;
        float v0 = acc[m][0][g4 * 4 + r4];
        float v1 = acc[m][1][g4 * 4 + r4];
        if (accumulate) { v0 += bf2f(cp[0]); v1 += bf2f(cp[32]); }
        cp[0]  = f2bf(v0);
        cp[32] = f2bf(v1);
      }
    }
  }
}

// ---------------------------------------------------------------------------
// 6) row softmax: reads bf16 logits, writes fp8 attn*448 K-group-major
__global__ __launch_bounds__(256) void softmax_rows_k(
    const unsigned short* __restrict__ Lb, unsigned char* __restrict__ Att)
{
  const int q = blockIdx.x;
  const unsigned short* row = Lb + (size_t)q * 3840;
  const int tid = threadIdx.x;
  float v[15];
  float mx = -1e30f;
  #pragma unroll
  for (int j = 0; j < 15; ++j) {
    int s = tid + j * 256;
    float x = (s < 3600) ? bf2f(row[s]) : -1e30f;
    v[j] = x;
    mx = fmaxf(mx, x);
  }
  #pragma unroll
  for (int o = 32; o > 0; o >>= 1) mx = fmaxf(mx, __shfl_xor(mx, o));
  __shared__ float wmax[4], wsum[4];
  if ((tid & 63) == 0) wmax[tid >> 6] = mx;
  __syncthreads();
  mx = fmaxf(fmaxf(wmax[0], wmax[1]), fmaxf(wmax[2], wmax[3]));
  float sum = 0.f;
  #pragma unroll
  for (int j = 0; j < 15; ++j) {
    int s = tid + j * 256;
    float e = (s < 3600) ? __expf(v[j] - mx) : 0.f;
    v[j] = e;
    sum += e;
  }
  #pragma unroll
  for (int o = 32; o > 0; o >>= 1) sum += __shfl_xor(sum, o);
  if ((tid & 63) == 0) wsum[tid >> 6] = sum;
  __syncthreads();
  sum = wsum[0] + wsum[1] + wsum[2] + wsum[3];
  const float inv448 = 448.0f / sum;
  #pragma unroll
  for (int j = 0; j < 15; ++j) {
    int s = tid + j * 256;
    unsigned char b = (s < 3600) ? f2e4m3(v[j] * inv448) : (unsigned char)0;
    Att[((size_t)(s >> 4) * 3840 + q) * 16 + (s & 15)] = b;
  }
}

// ---------------------------------------------------------------------------
// 7) out[c][p] = 0.5*f_q[c][p] + (0.25/448)*sum_z P[z][p][c]  (bf16 partials)
__global__ __launch_bounds__(256) void final_blend_k(
    const unsigned short* __restrict__ P, const float* __restrict__ fq,
    float* __restrict__ out)
{
  __shared__ float t[32][33];
  const int tx = threadIdx.x, ty = threadIdx.y;
  const int p0 = blockIdx.x * 32, c0 = blockIdx.y * 32;
  const long ZC = 3840L * 512;
  #pragma unroll
  for (int i = 0; i < 4; ++i) {
    int p = p0 + ty + i * 8, c = c0 + tx;
    float s = 0.f;
    if (p < 3600) {
      size_t o = (size_t)p * 512 + c;
      #pragma unroll
      for (int z = 0; z < 6; ++z) s += bf2f(P[o + (size_t)z * ZC]);
    }
    t[ty + i * 8][tx] = s;
  }
  __syncthreads();
  const float wts = 0.25f / 448.0f;
  #pragma unroll
  for (int i = 0; i < 4; ++i) {
    int c = c0 + ty + i * 8, p = p0 + tx;
    if (p < 3600) {
      size_t o = (size_t)c * 3600 + p;
      out[o] = 0.5f * fq[o] + wts * t[tx][ty + i * 8];
    }
  }
}

// ---------------------------------------------------------------------------
extern "C" void kernel_launch(void* const* d_in, const int* in_sizes, int n_in,
                              void* d_out, int out_size, void* d_ws, size_t ws_size,
                              hipStream_t stream) {
  const float* fq3 = (const float*)d_in[0];
  const float* fq4 = (const float*)d_in[1];
  const float* fs3 = (const float*)d_in[2];
  const float* fs4 = (const float*)d_in[3];
  const float* f_q = (const float*)d_in[4];
  const float* f_s = (const float*)d_in[5];
  const float* wch = (const float*)d_in[6];
  float* out = (float*)d_out;

  const size_t HW = 3600, MP = 3840, KC = 3072, CH = 512;

  // workspace (~94 MB)
  unsigned char* QT8 = (unsigned char*)d_ws;          // (KC/16, MP, 16B) fp8 query
  unsigned char* ST8 = QT8 + MP * KC;                 // (KC/16, MP, 16B) fp8 support
  unsigned char* V8  = ST8 + MP * KC;                 // (MP/16, CH, 16B) fp8 V
  unsigned short* Lb = (unsigned short*)(V8 + (MP / 16) * CH * 16);  // (MP,MP) bf16 logits
  unsigned char* Att8 = (unsigned char*)(Lb + MP * MP);  // (MP/16, MP, 16B) fp8 attn*448
  unsigned short* Pb = (unsigned short*)(Att8 + (MP / 16) * MP * 16); // 6 x (MP,CH) bf16
  float* invn = (float*)(Pb + 6 * MP * CH);           // 6 x 3600
  float* part = (float*)Lb;                           // norm scratch (consumed pre-GEMM)

  Src6 S;
  S.p[0] = fq4; S.p[1] = fs4; S.p[2] = fs4 + 2048 * HW;
  S.p[3] = fq3; S.p[4] = fs3; S.p[5] = fs3 + 1024 * HW;
  colnorm_part6_k<<<dim3(57, 16, 6), 256, 0, stream>>>(S, part);
  colnorm_fin6_k<<<dim3(15, 6), 256, 0, stream>>>(part, invn);

  dim3 tb(32, 8);
  tpose2_f8_k<<<dim3(113, 96), tb, 0, stream>>>(fq4, fq3, invn + 0 * HW, invn + 3 * HW,
                                                wch, 1, QT8);

  for (int b = 0; b < 2; ++b) {
    castv_f8_k<<<7200, 256, 0, stream>>>(f_s + (size_t)b * CH * HW, V8);
    tpose2_f8_k<<<dim3(113, 96), tb, 0, stream>>>(
        fs4 + (size_t)b * 2048 * HW, fs3 + (size_t)b * 1024 * HW,
        invn + (1 + b) * HW, invn + (4 + b) * HW, wch, 0, ST8);

    // logits (bf16) = QT8 . ST8^T (MX-fp8, unit scales); 30x30 = 900 blocks
    gemm128_f8<<<900, 256, 0, stream>>>(QT8, ST8, Lb, 3072, 3840, 3840, 30);

    softmax_rows_k<<<3600, 256, 0, stream>>>(Lb, Att8);

    // PV split-K=6, fp8 x fp8 -> bf16 partials (scale 448 folded in attn)
    pv_f8_k<<<dim3(30, 4, 6), 256, 0, stream>>>(Att8, V8, Pb, b);
  }

  final_blend_k<<<dim3(113, 16), tb, 0, stream>>>(Pb, f_q, out);
}